// Round 2
// baseline (2464.248 us; speedup 1.0000x reference)
//
#include <hip/hip_runtime.h>
#include <math.h>

// Sizes (fixed by the problem): N=16384, IN_DIM=512, HID=256, E=262144.
// GEMM assumes M%128==0, N%128==0, K%16==0 — true for both calls.
//
// Numerics: output threshold is 2e-2 vs an f64 reference; logits ~N(0,1e4)
// with ~170 edges near sigmoid's transition => need |dZ| <~ 2e-4.
// Hierarchical (per-16-k-tile) accumulation cuts sequential-fp32 error ~10x:
// measured R0 absmax 0.0234 with naive accumulation -> predicted ~0.003 here.

#define BM 128
#define BN 128
#define BK 16
#define LDAS (BM + 4)
#define LDBS (BN + 4)

__global__ __launch_bounds__(256, 1)
void gemm_f32_nn(const float* __restrict__ A, const float* __restrict__ B,
                 float* __restrict__ C, int M, int N, int K)
{
  __shared__ float As[2][BK][LDAS];  // A^T tile: [k][m]
  __shared__ float Bs[2][BK][LDBS];  // B tile:  [k][n]

  const int tid = threadIdx.x;
  const int tx = tid & 15;   // n-direction (16 threads)
  const int ty = tid >> 4;   // m-direction (16 threads)
  const long m0 = (long)blockIdx.x * BM;
  const long n0 = (long)blockIdx.y * BN;

  const int a_row = tid >> 2;         // 0..63
  const int a_kc  = (tid & 3) << 2;   // 0,4,8,12
  const int b_row = tid >> 5;         // 0..7
  const int b_col = (tid & 31) << 2;  // 0..124

  const float* Ag0 = A + (m0 + a_row) * (long)K + a_kc;
  const float* Ag1 = A + (m0 + 64 + a_row) * (long)K + a_kc;
  const float* Bg0 = B + (long)b_row * N + n0 + b_col;
  const float* Bg1 = B + (long)(b_row + 8) * N + n0 + b_col;

  float4 av0 = *(const float4*)(Ag0);
  float4 av1 = *(const float4*)(Ag1);
  float4 bv0 = *(const float4*)(Bg0);
  float4 bv1 = *(const float4*)(Bg1);

  float acc[8][8];
#pragma unroll
  for (int i = 0; i < 8; ++i)
#pragma unroll
    for (int j = 0; j < 8; ++j) acc[i][j] = 0.f;

  const int nt = K / BK;
  int buf = 0;

#pragma unroll
  for (int i = 0; i < 4; ++i) {
    As[0][a_kc + i][a_row]      = (&av0.x)[i];
    As[0][a_kc + i][a_row + 64] = (&av1.x)[i];
  }
  *(float4*)&Bs[0][b_row][b_col]     = bv0;
  *(float4*)&Bs[0][b_row + 8][b_col] = bv1;
  __syncthreads();

  for (int t = 0; t < nt; ++t) {
    if (t + 1 < nt) {
      const long ko = (long)(t + 1) * BK;
      av0 = *(const float4*)(Ag0 + ko);
      av1 = *(const float4*)(Ag1 + ko);
      bv0 = *(const float4*)(Bg0 + ko * N);
      bv1 = *(const float4*)(Bg1 + ko * N);
    }
    // tile-local accumulator: bounds partial-sum magnitude to the 16-term
    // tile sum, so the rounding at |acc|~85 happens once per tile not 16x.
    float tacc[8][8];
#pragma unroll
    for (int i = 0; i < 8; ++i)
#pragma unroll
      for (int j = 0; j < 8; ++j) tacc[i][j] = 0.f;

#pragma unroll
    for (int kk = 0; kk < BK; ++kk) {
      float4 aA = *(const float4*)&As[buf][kk][ty * 4];
      float4 aB = *(const float4*)&As[buf][kk][ty * 4 + 64];
      float4 bA = *(const float4*)&Bs[buf][kk][tx * 4];
      float4 bB = *(const float4*)&Bs[buf][kk][tx * 4 + 64];
      const float ar[8] = {aA.x, aA.y, aA.z, aA.w, aB.x, aB.y, aB.z, aB.w};
      const float br[8] = {bA.x, bA.y, bA.z, bA.w, bB.x, bB.y, bB.z, bB.w};
#pragma unroll
      for (int i = 0; i < 8; ++i)
#pragma unroll
        for (int j = 0; j < 8; ++j)
          tacc[i][j] = fmaf(ar[i], br[j], tacc[i][j]);
    }
#pragma unroll
    for (int i = 0; i < 8; ++i)
#pragma unroll
      for (int j = 0; j < 8; ++j) acc[i][j] += tacc[i][j];

    if (t + 1 < nt) {
      const int nb = buf ^ 1;
#pragma unroll
      for (int i = 0; i < 4; ++i) {
        As[nb][a_kc + i][a_row]      = (&av0.x)[i];
        As[nb][a_kc + i][a_row + 64] = (&av1.x)[i];
      }
      *(float4*)&Bs[nb][b_row][b_col]     = bv0;
      *(float4*)&Bs[nb][b_row + 8][b_col] = bv1;
    }
    __syncthreads();
    buf ^= 1;
  }

#pragma unroll
  for (int i = 0; i < 8; ++i) {
    const long row = m0 + (i < 4 ? ty * 4 + i : 64 + ty * 4 + (i - 4));
#pragma unroll
    for (int c = 0; c < 2; ++c) {
      float4 v;
      v.x = acc[i][c * 4 + 0];
      v.y = acc[i][c * 4 + 1];
      v.z = acc[i][c * 4 + 2];
      v.w = acc[i][c * 4 + 3];
      *(float4*)&C[row * N + n0 + tx * 4 + c * 64] = v;
    }
  }
}

// One wave64 per edge: lane covers h = 4*lane..4*lane+3 of the 256-wide rows.
__global__ __launch_bounds__(256)
void edge_score(const float* __restrict__ Z, const float* __restrict__ w2,
                const int* __restrict__ te, const int* __restrict__ fe,
                int E, float* __restrict__ out)
{
  const long gtid = (long)blockIdx.x * 256 + threadIdx.x;
  const long wid = gtid >> 6;
  const int lane = threadIdx.x & 63;
  if (wid >= 2L * E) return;
  const int* ep = (wid < E) ? (te + 2 * wid) : (fe + 2 * (wid - E));
  const int src = ep[0];
  const int dst = ep[1];
  const float4 a = ((const float4*)(Z + (long)src * 256))[lane];
  const float4 b = ((const float4*)(Z + (long)dst * 256))[lane];
  const float4 w = ((const float4*)w2)[lane];
  float s = a.x * b.x * w.x + a.y * b.y * w.y + a.z * b.z * w.z + a.w * b.w * w.w;
#pragma unroll
  for (int off = 32; off > 0; off >>= 1) s += __shfl_down(s, off);
  if (lane == 0) out[wid] = 1.0f / (1.0f + expf(-s));
}

extern "C" void kernel_launch(void* const* d_in, const int* in_sizes, int n_in,
                              void* d_out, int out_size, void* d_ws, size_t ws_size,
                              hipStream_t stream)
{
  const float* X   = (const float*)d_in[0];
  const float* adj = (const float*)d_in[1];
  const float* W   = (const float*)d_in[2];
  const float* W2  = (const float*)d_in[3];
  const int*   te  = (const int*)d_in[4];
  const int*   fe  = (const int*)d_in[5];

  const int Nn  = 16384;
  const int IN  = 512;
  const int HID = 256;
  const int E   = in_sizes[4] / 2;

  float* XW = (float*)d_ws;                    // 16384*256 f32 = 16.8 MB
  float* Z  = XW + (long)Nn * HID;             // 16384*256 f32 = 16.8 MB

  dim3 blk(256);
  // XW = X @ weight   (M=16384, N=256, K=512)
  gemm_f32_nn<<<dim3(Nn / BM, HID / BN), blk, 0, stream>>>(X, W, XW, Nn, HID, IN);
  // Z = adj @ XW      (M=16384, N=256, K=16384)  -- the 137 GFLOP GEMM
  gemm_f32_nn<<<dim3(Nn / BM, HID / BN), blk, 0, stream>>>(adj, XW, Z, Nn, HID, Nn);

  const long nwaves = 2L * E;
  const int nblocks = (int)((nwaves + 3) / 4);
  edge_score<<<dim3(nblocks), blk, 0, stream>>>(Z, W2, te, fe, E, (float*)d_out);
}

// Round 3
// 1603.034 us; speedup vs baseline: 1.5372x; 1.5372x over previous
//
#include <hip/hip_runtime.h>
#include <math.h>

// N=16384, IN=512, HID=256, E=262144.
// Z = adj @ (X@W) via split-3 bf16 MFMA (6 cross-products = one bf16 GEMM
// with consistent A/B k-linearization); logits via per-edge wave reduce.
//
// Numerics: residual of 3-term bf16 split ~2^-27 rel (negligible); dominant
// error = fp32 MFMA accum chain (1536 adds/partial, splitK=2) -> dz ~ 8e-5,
// below R1's measured-passing 1.1e-4 (absmax 0.0078 @ threshold 0.02).

typedef __attribute__((ext_vector_type(8))) short short8v;
typedef __attribute__((ext_vector_type(4))) float floatx4;

#define NM_ (16384L * 256L)   // elements of XW / Z / partials

static __device__ __forceinline__ unsigned cvt_pk_bf16(float lo, float hi) {
  unsigned r;
  asm("v_cvt_pk_bf16_f32 %0, %1, %2" : "=v"(r) : "v"(lo), "v"(hi));
  return r;  // [15:0]=bf16(lo), [31:16]=bf16(hi), RNE
}

// split pair (x0,x1) into 3 bf16 levels, packed 2-per-uint
static __device__ __forceinline__ void split3_pair(float x0, float x1,
                                                   unsigned& q1, unsigned& q2, unsigned& q3) {
  q1 = cvt_pk_bf16(x0, x1);
  float f0 = __uint_as_float(q1 << 16);
  float f1 = __uint_as_float(q1 & 0xffff0000u);
  float d0 = x0 - f0, d1 = x1 - f1;           // exact
  q2 = cvt_pk_bf16(d0, d1);
  float g0 = __uint_as_float(q2 << 16);
  float g1 = __uint_as_float(q2 & 0xffff0000u);
  q3 = cvt_pk_bf16(d0 - g0, d1 - g1);
}

// ---------------- GEMM1: fp32 hierarchical (X @ W -> XW), small ----------------
#define BM 128
#define BN 128
#define BK 16
#define LDAS (BM + 4)
#define LDBS (BN + 4)

__global__ __launch_bounds__(256, 1)
void gemm_f32_nn(const float* __restrict__ A, const float* __restrict__ B,
                 float* __restrict__ C, int M, int N, int K)
{
  __shared__ float As[2][BK][LDAS];
  __shared__ float Bs[2][BK][LDBS];

  const int tid = threadIdx.x;
  const int tx = tid & 15;
  const int ty = tid >> 4;
  const long m0 = (long)blockIdx.x * BM;
  const long n0 = (long)blockIdx.y * BN;

  const int a_row = tid >> 2;
  const int a_kc  = (tid & 3) << 2;
  const int b_row = tid >> 5;
  const int b_col = (tid & 31) << 2;

  const float* Ag0 = A + (m0 + a_row) * (long)K + a_kc;
  const float* Ag1 = A + (m0 + 64 + a_row) * (long)K + a_kc;
  const float* Bg0 = B + (long)b_row * N + n0 + b_col;
  const float* Bg1 = B + (long)(b_row + 8) * N + n0 + b_col;

  float4 av0 = *(const float4*)(Ag0);
  float4 av1 = *(const float4*)(Ag1);
  float4 bv0 = *(const float4*)(Bg0);
  float4 bv1 = *(const float4*)(Bg1);

  float acc[8][8];
#pragma unroll
  for (int i = 0; i < 8; ++i)
#pragma unroll
    for (int j = 0; j < 8; ++j) acc[i][j] = 0.f;

  const int nt = K / BK;
  int buf = 0;

#pragma unroll
  for (int i = 0; i < 4; ++i) {
    As[0][a_kc + i][a_row]      = (&av0.x)[i];
    As[0][a_kc + i][a_row + 64] = (&av1.x)[i];
  }
  *(float4*)&Bs[0][b_row][b_col]     = bv0;
  *(float4*)&Bs[0][b_row + 8][b_col] = bv1;
  __syncthreads();

  for (int t = 0; t < nt; ++t) {
    if (t + 1 < nt) {
      const long ko = (long)(t + 1) * BK;
      av0 = *(const float4*)(Ag0 + ko);
      av1 = *(const float4*)(Ag1 + ko);
      bv0 = *(const float4*)(Bg0 + ko * N);
      bv1 = *(const float4*)(Bg1 + ko * N);
    }
    float tacc[8][8];
#pragma unroll
    for (int i = 0; i < 8; ++i)
#pragma unroll
      for (int j = 0; j < 8; ++j) tacc[i][j] = 0.f;

#pragma unroll
    for (int kk = 0; kk < BK; ++kk) {
      float4 aA = *(const float4*)&As[buf][kk][ty * 4];
      float4 aB = *(const float4*)&As[buf][kk][ty * 4 + 64];
      float4 bA = *(const float4*)&Bs[buf][kk][tx * 4];
      float4 bB = *(const float4*)&Bs[buf][kk][tx * 4 + 64];
      const float ar[8] = {aA.x, aA.y, aA.z, aA.w, aB.x, aB.y, aB.z, aB.w};
      const float br[8] = {bA.x, bA.y, bA.z, bA.w, bB.x, bB.y, bB.z, bB.w};
#pragma unroll
      for (int i = 0; i < 8; ++i)
#pragma unroll
        for (int j = 0; j < 8; ++j)
          tacc[i][j] = fmaf(ar[i], br[j], tacc[i][j]);
    }
#pragma unroll
    for (int i = 0; i < 8; ++i)
#pragma unroll
      for (int j = 0; j < 8; ++j) acc[i][j] += tacc[i][j];

    if (t + 1 < nt) {
      const int nb = buf ^ 1;
#pragma unroll
      for (int i = 0; i < 4; ++i) {
        As[nb][a_kc + i][a_row]      = (&av0.x)[i];
        As[nb][a_kc + i][a_row + 64] = (&av1.x)[i];
      }
      *(float4*)&Bs[nb][b_row][b_col]     = bv0;
      *(float4*)&Bs[nb][b_row + 8][b_col] = bv1;
    }
    __syncthreads();
    buf ^= 1;
  }

#pragma unroll
  for (int i = 0; i < 8; ++i) {
    const long row = m0 + (i < 4 ? ty * 4 + i : 64 + ty * 4 + (i - 4));
#pragma unroll
    for (int c = 0; c < 2; ++c) {
      float4 v;
      v.x = acc[i][c * 4 + 0];
      v.y = acc[i][c * 4 + 1];
      v.z = acc[i][c * 4 + 2];
      v.w = acc[i][c * 4 + 3];
      *(float4*)&C[row * N + n0 + tx * 4 + c * 64] = v;
    }
  }
}

// -------- transpose + split XW[16384][256] -> XT_s[256][16384] bf16 x3 --------
__global__ __launch_bounds__(256)
void transpose_split(const float* __restrict__ XW,
                     unsigned short* __restrict__ X1,
                     unsigned short* __restrict__ X2,
                     unsigned short* __restrict__ X3)
{
  __shared__ float T[64][65];
  const int tid = threadIdx.x;
  const long kb = (long)blockIdx.x * 64;   // XW row (k) tile
  const long nb = (long)blockIdx.y * 64;   // XW col (n) tile

#pragma unroll
  for (int i = 0; i < 4; ++i) {
    int idx = tid + 256 * i;
    int r = idx >> 4, c4 = (idx & 15) * 4;
    float4 v = *(const float4*)&XW[(kb + r) * 256 + nb + c4];
    T[r][c4 + 0] = v.x; T[r][c4 + 1] = v.y; T[r][c4 + 2] = v.z; T[r][c4 + 3] = v.w;
  }
  __syncthreads();

#pragma unroll
  for (int i = 0; i < 2; ++i) {
    int idx = tid + 256 * i;
    int n = idx >> 3, kq = (idx & 7) * 8;
    float x[8];
#pragma unroll
    for (int j = 0; j < 8; ++j) x[j] = T[kq + j][n];
    unsigned q1[4], q2[4], q3[4];
#pragma unroll
    for (int p = 0; p < 4; ++p)
      split3_pair(x[2 * p], x[2 * p + 1], q1[p], q2[p], q3[p]);
    const long o = (nb + n) * 16384L + kb + kq;
    *(uint4*)&X1[o] = make_uint4(q1[0], q1[1], q1[2], q1[3]);
    *(uint4*)&X2[o] = make_uint4(q2[0], q2[1], q2[2], q2[3]);
    *(uint4*)&X3[o] = make_uint4(q3[0], q3[1], q3[2], q3[3]);
  }
}

// ---------------- GEMM2: Z = adj @ XW via split-3 bf16 MFMA ----------------
#define TBM 128
#define TBN 128
#define ASTR 40       // ushorts per LDS row (80 B, 16B-aligned, 2-way max conflict)
#define KT_PER 256    // k-tiles (of 32) per split-K block

__global__ __launch_bounds__(256, 2)
void gemm_split3(const float* __restrict__ A,
                 const unsigned short* __restrict__ B1,
                 const unsigned short* __restrict__ B2,
                 const unsigned short* __restrict__ B3,
                 float* __restrict__ P0, float* __restrict__ P1)
{
  __shared__ unsigned short As[3][TBM * ASTR];  // 30720 B
  __shared__ unsigned short Bs[3][TBN * ASTR];  // 30720 B

  const int tid  = threadIdx.x;
  const int lane = tid & 63;
  const int w    = tid >> 6;
  const int wm   = w >> 1, wn = w & 1;
  const long m0 = (long)blockIdx.x * TBM;
  const long n0 = (long)blockIdx.y * TBN;
  const long kbase = (long)blockIdx.z * (KT_PER * 32L);
  float* __restrict__ Cp = blockIdx.z ? P1 : P0;

  // A staging: 4 float4/thread: rows ar+32i, f4-chunk akq
  const int ar  = tid >> 3;
  const int akq = tid & 7;
  const float* AgB = A + (m0 + ar) * 16384L + kbase + akq * 4;

  // B staging: per split 2 uint4/thread: rows bn+64i, 16B-chunk bkq
  const int bn  = tid >> 2;
  const int bkq = tid & 3;
  const unsigned short* B1p = B1 + (n0 + bn) * 16384L + kbase + bkq * 8;
  const unsigned short* B2p = B2 + (n0 + bn) * 16384L + kbase + bkq * 8;
  const unsigned short* B3p = B3 + (n0 + bn) * 16384L + kbase + bkq * 8;

  floatx4 acc[4][4];
#pragma unroll
  for (int i = 0; i < 4; ++i)
#pragma unroll
    for (int j = 0; j < 4; ++j) acc[i][j] = (floatx4)0.f;

  const int aWr = ar * ASTR + akq * 4;              // LDS write base (ushort units)
  const int bWr = bn * ASTR + bkq * 8;
  const int aRd = (wm * 64 + (lane & 15)) * ASTR + (lane >> 4) * 8;
  const int bRd = (wn * 64 + (lane & 15)) * ASTR + (lane >> 4) * 8;

  float4 pa[4];
  uint4  pb[3][2];
#pragma unroll
  for (int i = 0; i < 4; ++i) pa[i] = *(const float4*)(AgB + i * 32 * 16384L);
#pragma unroll
  for (int i = 0; i < 2; ++i) {
    pb[0][i] = *(const uint4*)(B1p + i * 64 * 16384L);
    pb[1][i] = *(const uint4*)(B2p + i * 64 * 16384L);
    pb[2][i] = *(const uint4*)(B3p + i * 64 * 16384L);
  }

  for (int t = 0; t < KT_PER; ++t) {
    __syncthreads();   // previous tile's frag reads complete
    // ---- write A splits (convert f32 -> 3x bf16) ----
#pragma unroll
    for (int i = 0; i < 4; ++i) {
      const float* px = (const float*)&pa[i];
      unsigned q1[2], q2[2], q3[2];
#pragma unroll
      for (int c = 0; c < 2; ++c)
        split3_pair(px[2 * c], px[2 * c + 1], q1[c], q2[c], q3[c]);
      const int adr = aWr + i * 32 * ASTR;
      *(uint2*)&As[0][adr] = make_uint2(q1[0], q1[1]);
      *(uint2*)&As[1][adr] = make_uint2(q2[0], q2[1]);
      *(uint2*)&As[2][adr] = make_uint2(q3[0], q3[1]);
    }
    // ---- write B splits ----
#pragma unroll
    for (int i = 0; i < 2; ++i) {
      const int bdr = bWr + i * 64 * ASTR;
      *(uint4*)&Bs[0][bdr] = pb[0][i];
      *(uint4*)&Bs[1][bdr] = pb[1][i];
      *(uint4*)&Bs[2][bdr] = pb[2][i];
    }
    __syncthreads();
    // ---- prefetch next tile ----
    if (t + 1 < KT_PER) {
      const long ko = (long)(t + 1) * 32;
#pragma unroll
      for (int i = 0; i < 4; ++i) pa[i] = *(const float4*)(AgB + i * 32 * 16384L + ko);
#pragma unroll
      for (int i = 0; i < 2; ++i) {
        pb[0][i] = *(const uint4*)(B1p + i * 64 * 16384L + ko);
        pb[1][i] = *(const uint4*)(B2p + i * 64 * 16384L + ko);
        pb[2][i] = *(const uint4*)(B3p + i * 64 * 16384L + ko);
      }
    }
    // ---- fragment reads ----
    short8v af[3][4], bf[3][4];
#pragma unroll
    for (int f = 0; f < 4; ++f) {
#pragma unroll
      for (int s = 0; s < 3; ++s) {
        af[s][f] = *(const short8v*)&As[s][aRd + f * 16 * ASTR];
        bf[s][f] = *(const short8v*)&Bs[s][bRd + f * 16 * ASTR];
      }
    }
    // ---- 96 MFMAs: 6 split-products per 16x16 frag ----
#pragma unroll
    for (int fm = 0; fm < 4; ++fm) {
#pragma unroll
      for (int fn = 0; fn < 4; ++fn) {
        floatx4 d = acc[fm][fn];
        d = __builtin_amdgcn_mfma_f32_16x16x32_bf16(af[0][fm], bf[0][fn], d, 0, 0, 0);
        d = __builtin_amdgcn_mfma_f32_16x16x32_bf16(af[0][fm], bf[1][fn], d, 0, 0, 0);
        d = __builtin_amdgcn_mfma_f32_16x16x32_bf16(af[1][fm], bf[0][fn], d, 0, 0, 0);
        d = __builtin_amdgcn_mfma_f32_16x16x32_bf16(af[1][fm], bf[1][fn], d, 0, 0, 0);
        d = __builtin_amdgcn_mfma_f32_16x16x32_bf16(af[0][fm], bf[2][fn], d, 0, 0, 0);
        d = __builtin_amdgcn_mfma_f32_16x16x32_bf16(af[2][fm], bf[0][fn], d, 0, 0, 0);
        acc[fm][fn] = d;
      }
    }
  }

  // epilogue: C/D layout col=lane&15, row=(lane>>4)*4+j  [m89]
#pragma unroll
  for (int fm = 0; fm < 4; ++fm) {
#pragma unroll
    for (int fn = 0; fn < 4; ++fn) {
      const long col = n0 + wn * 64 + fn * 16 + (lane & 15);
      const long rowb = m0 + wm * 64 + fm * 16 + (lane >> 4) * 4;
#pragma unroll
      for (int j = 0; j < 4; ++j)
        Cp[(rowb + j) * 256 + col] = acc[fm][fn][j];
    }
  }
}

// ---------------- P1 += P0 (Z = sum of split-K partials) ----------------
__global__ __launch_bounds__(256)
void reduce_add(const float* __restrict__ P0, float* __restrict__ P1, long n4)
{
  long i = (long)blockIdx.x * 256 + threadIdx.x;
  const long stride = (long)gridDim.x * 256;
  for (; i < n4; i += stride) {
    float4 a = ((const float4*)P0)[i];
    float4 b = ((const float4*)P1)[i];
    b.x += a.x; b.y += a.y; b.z += a.z; b.w += a.w;
    ((float4*)P1)[i] = b;
  }
}

// ---------------- edge scoring ----------------
__global__ __launch_bounds__(256)
void edge_score(const float* __restrict__ Z, const float* __restrict__ w2,
                const int* __restrict__ te, const int* __restrict__ fe,
                int E, float* __restrict__ out)
{
  const long gtid = (long)blockIdx.x * 256 + threadIdx.x;
  const long wid = gtid >> 6;
  const int lane = threadIdx.x & 63;
  if (wid >= 2L * E) return;
  const int* ep = (wid < E) ? (te + 2 * wid) : (fe + 2 * (wid - E));
  const int src = ep[0];
  const int dst = ep[1];
  const float4 a = ((const float4*)(Z + (long)src * 256))[lane];
  const float4 b = ((const float4*)(Z + (long)dst * 256))[lane];
  const float4 w = ((const float4*)w2)[lane];
  float s = a.x * b.x * w.x + a.y * b.y * w.y + a.z * b.z * w.z + a.w * b.w * w.w;
#pragma unroll
  for (int off = 32; off > 0; off >>= 1) s += __shfl_down(s, off);
  if (lane == 0) out[wid] = 1.0f / (1.0f + expf(-s));
}

extern "C" void kernel_launch(void* const* d_in, const int* in_sizes, int n_in,
                              void* d_out, int out_size, void* d_ws, size_t ws_size,
                              hipStream_t stream)
{
  const float* X   = (const float*)d_in[0];
  const float* adj = (const float*)d_in[1];
  const float* W   = (const float*)d_in[2];
  const float* W2  = (const float*)d_in[3];
  const int*   te  = (const int*)d_in[4];
  const int*   fe  = (const int*)d_in[5];

  const int E = in_sizes[4] / 2;

  float* ws = (float*)d_ws;
  float* XW = ws;                    // dead after transpose_split; reused as P0
  float* P0 = ws;
  float* P1 = ws + NM_;              // final Z lives here
  unsigned short* X1 = (unsigned short*)(ws + 2 * NM_);
  unsigned short* X2 = X1 + NM_;
  unsigned short* X3 = X2 + NM_;
  // total ws use: 2*NM*4 + 3*NM*2 = 58.7 MB

  dim3 blk(256);
  // XW = X @ W  (fp32, hierarchical)
  gemm_f32_nn<<<dim3(128, 2), blk, 0, stream>>>(X, W, XW, 16384, 256, 512);
  // XT1/2/3 = split3(XW)^T
  transpose_split<<<dim3(256, 4), blk, 0, stream>>>(XW, X1, X2, X3);
  // Z partials = adj @ XW  (split-3 bf16 MFMA, splitK=2)
  gemm_split3<<<dim3(128, 2, 2), blk, 0, stream>>>(adj, X1, X2, X3, P0, P1);
  // Z = P0 + P1 (into P1)
  reduce_add<<<dim3(2048), blk, 0, stream>>>(P0, P1, NM_ / 4);
  // edge logits + sigmoid
  const long nwaves = 2L * E;
  const int nblocks = (int)((nwaves + 3) / 4);
  edge_score<<<dim3(nblocks), blk, 0, stream>>>(P1, W2, te, fe, E, (float*)d_out);
}

// Round 4
// 933.974 us; speedup vs baseline: 2.6385x; 1.7164x over previous
//
#include <hip/hip_runtime.h>
#include <math.h>

// N=16384, IN=512, HID=256, E=262144.
// Z = adj @ (X@W) via split-3 bf16 MFMA (6 cross-products, consistent A/B
// k-linearization). R3: conflict-free chunk-major LDS, global_load_lds DMA
// for B (pre-tiled by transpose_split), raw-barrier pipeline, chunked acc.

typedef __attribute__((ext_vector_type(8))) short short8v;
typedef __attribute__((ext_vector_type(4))) float floatx4;

#define NM_ (16384L * 256L)
#define KT 256   // 32-wide k-tiles per split-K half (8192 k)

static __device__ __forceinline__ unsigned cvt_pk_bf16(float lo, float hi) {
  unsigned r;
  asm("v_cvt_pk_bf16_f32 %0, %1, %2" : "=v"(r) : "v"(lo), "v"(hi));
  return r;  // [15:0]=bf16(lo), [31:16]=bf16(hi), RNE
}

static __device__ __forceinline__ void split3_pair(float x0, float x1,
                                                   unsigned& q1, unsigned& q2, unsigned& q3) {
  q1 = cvt_pk_bf16(x0, x1);
  float f0 = __uint_as_float(q1 << 16);
  float f1 = __uint_as_float(q1 & 0xffff0000u);
  float d0 = x0 - f0, d1 = x1 - f1;           // exact
  q2 = cvt_pk_bf16(d0, d1);
  float g0 = __uint_as_float(q2 << 16);
  float g1 = __uint_as_float(q2 & 0xffff0000u);
  q3 = cvt_pk_bf16(d0 - g0, d1 - g1);
}

static __device__ __forceinline__ void gload_lds16(const void* g, void* l) {
  __builtin_amdgcn_global_load_lds(
      (const __attribute__((address_space(1))) unsigned*)g,
      (__attribute__((address_space(3))) unsigned*)l, 16, 0, 0);
}

// ---------------- GEMM1: fp32 hierarchical (X @ W -> XW) ----------------
#define BM 128
#define BN 128
#define BK 16
#define LDAS (BM + 4)
#define LDBS (BN + 4)

__global__ __launch_bounds__(256, 1)
void gemm_f32_nn(const float* __restrict__ A, const float* __restrict__ B,
                 float* __restrict__ C, int M, int N, int K)
{
  __shared__ float As[2][BK][LDAS];
  __shared__ float Bs[2][BK][LDBS];

  const int tid = threadIdx.x;
  const int tx = tid & 15;
  const int ty = tid >> 4;
  const long m0 = (long)blockIdx.x * BM;
  const long n0 = (long)blockIdx.y * BN;

  const int a_row = tid >> 2;
  const int a_kc  = (tid & 3) << 2;
  const int b_row = tid >> 5;
  const int b_col = (tid & 31) << 2;

  const float* Ag0 = A + (m0 + a_row) * (long)K + a_kc;
  const float* Ag1 = A + (m0 + 64 + a_row) * (long)K + a_kc;
  const float* Bg0 = B + (long)b_row * N + n0 + b_col;
  const float* Bg1 = B + (long)(b_row + 8) * N + n0 + b_col;

  float4 av0 = *(const float4*)(Ag0);
  float4 av1 = *(const float4*)(Ag1);
  float4 bv0 = *(const float4*)(Bg0);
  float4 bv1 = *(const float4*)(Bg1);

  float acc[8][8];
#pragma unroll
  for (int i = 0; i < 8; ++i)
#pragma unroll
    for (int j = 0; j < 8; ++j) acc[i][j] = 0.f;

  const int nt = K / BK;
  int buf = 0;

#pragma unroll
  for (int i = 0; i < 4; ++i) {
    As[0][a_kc + i][a_row]      = (&av0.x)[i];
    As[0][a_kc + i][a_row + 64] = (&av1.x)[i];
  }
  *(float4*)&Bs[0][b_row][b_col]     = bv0;
  *(float4*)&Bs[0][b_row + 8][b_col] = bv1;
  __syncthreads();

  for (int t = 0; t < nt; ++t) {
    if (t + 1 < nt) {
      const long ko = (long)(t + 1) * BK;
      av0 = *(const float4*)(Ag0 + ko);
      av1 = *(const float4*)(Ag1 + ko);
      bv0 = *(const float4*)(Bg0 + ko * N);
      bv1 = *(const float4*)(Bg1 + ko * N);
    }
    float tacc[8][8];
#pragma unroll
    for (int i = 0; i < 8; ++i)
#pragma unroll
      for (int j = 0; j < 8; ++j) tacc[i][j] = 0.f;

#pragma unroll
    for (int kk = 0; kk < BK; ++kk) {
      float4 aA = *(const float4*)&As[buf][kk][ty * 4];
      float4 aB = *(const float4*)&As[buf][kk][ty * 4 + 64];
      float4 bA = *(const float4*)&Bs[buf][kk][tx * 4];
      float4 bB = *(const float4*)&Bs[buf][kk][tx * 4 + 64];
      const float ar[8] = {aA.x, aA.y, aA.z, aA.w, aB.x, aB.y, aB.z, aB.w};
      const float br[8] = {bA.x, bA.y, bA.z, bA.w, bB.x, bB.y, bB.z, bB.w};
#pragma unroll
      for (int i = 0; i < 8; ++i)
#pragma unroll
        for (int j = 0; j < 8; ++j)
          tacc[i][j] = fmaf(ar[i], br[j], tacc[i][j]);
    }
#pragma unroll
    for (int i = 0; i < 8; ++i)
#pragma unroll
      for (int j = 0; j < 8; ++j) acc[i][j] += tacc[i][j];

    if (t + 1 < nt) {
      const int nb = buf ^ 1;
#pragma unroll
      for (int i = 0; i < 4; ++i) {
        As[nb][a_kc + i][a_row]      = (&av0.x)[i];
        As[nb][a_kc + i][a_row + 64] = (&av1.x)[i];
      }
      *(float4*)&Bs[nb][b_row][b_col]     = bv0;
      *(float4*)&Bs[nb][b_row + 8][b_col] = bv1;
    }
    __syncthreads();
    buf ^= 1;
  }

#pragma unroll
  for (int i = 0; i < 8; ++i) {
    const long row = m0 + (i < 4 ? ty * 4 + i : 64 + ty * 4 + (i - 4));
#pragma unroll
    for (int c = 0; c < 2; ++c) {
      float4 v;
      v.x = acc[i][c * 4 + 0];
      v.y = acc[i][c * 4 + 1];
      v.z = acc[i][c * 4 + 2];
      v.w = acc[i][c * 4 + 3];
      *(float4*)&C[row * N + n0 + tx * 4 + c * 64] = v;
    }
  }
}

// ---- transpose + split3 XW -> DMA-ready tiles: [split][kt][c(4)][n(256)][8] ----
__global__ __launch_bounds__(256)
void transpose_split(const float* __restrict__ XW,
                     unsigned short* __restrict__ X1,
                     unsigned short* __restrict__ X2,
                     unsigned short* __restrict__ X3)
{
  __shared__ float T[64][65];
  const int tid = threadIdx.x;
  const long kb = (long)blockIdx.x * 64;   // XW row (k) tile
  const long nb = (long)blockIdx.y * 64;   // XW col (n) tile

#pragma unroll
  for (int i = 0; i < 4; ++i) {
    int idx = tid + 256 * i;
    int r = idx >> 4, c4 = (idx & 15) * 4;
    float4 v = *(const float4*)&XW[(kb + r) * 256 + nb + c4];
    T[r][c4 + 0] = v.x; T[r][c4 + 1] = v.y; T[r][c4 + 2] = v.z; T[r][c4 + 3] = v.w;
  }
  __syncthreads();

#pragma unroll
  for (int i = 0; i < 2; ++i) {
    int idx = tid + 256 * i;
    int n = idx >> 3, kq = (idx & 7) * 8;   // 8 consecutive k for column nb+n
    float x[8];
#pragma unroll
    for (int j = 0; j < 8; ++j) x[j] = T[kq + j][n];
    unsigned q1[4], q2[4], q3[4];
#pragma unroll
    for (int p = 0; p < 4; ++p)
      split3_pair(x[2 * p], x[2 * p + 1], q1[p], q2[p], q3[p]);
    const long gk = kb + kq;
    const long gt = gk >> 5;                 // 32-wide k-tile
    const int  c  = (int)((gk >> 3) & 3);    // 16B chunk within tile
    const long o  = ((gt * 4 + c) * 256 + (nb + n)) * 8;
    *(uint4*)&X1[o] = make_uint4(q1[0], q1[1], q1[2], q1[3]);
    *(uint4*)&X2[o] = make_uint4(q2[0], q2[1], q2[2], q2[3]);
    *(uint4*)&X3[o] = make_uint4(q3[0], q3[1], q3[2], q3[3]);
  }
}

// ---------------- GEMM2: Z = adj @ XW, split-3 bf16 MFMA ----------------
// LDS chunk-major: panel[s][c][row][8 ushort]; all reads/writes 16-lane
// contiguous 16B => zero bank conflicts by construction.

__global__ __launch_bounds__(256, 2)
void gemm_split3(const float* __restrict__ A,
                 const unsigned short* __restrict__ Bg,   // 3 splits, stride NM_
                 float* __restrict__ P0, float* __restrict__ P1)
{
  __shared__ unsigned short As[12288];      // 3*4*128*8  = 24 KB
  __shared__ unsigned short Bs[2][12288];   // double-buffered, 48 KB

  const int tid  = threadIdx.x;
  const int lane = tid & 63;
  const int w    = tid >> 6;
  const int wm   = w >> 1, wn = w & 1;
  const long m0 = (long)blockIdx.x * 128;
  const long n0 = (long)blockIdx.y * 128;
  const int  z  = blockIdx.z;
  float* __restrict__ Cp = z ? P1 : P0;

  // A staging: thread -> (row = tid&127, k 16*ah..16*ah+15)
  const int arow = tid & 127;
  const int ah   = tid >> 7;
  const float* Ag = A + (m0 + arow) * 16384L + (long)z * 8192 + ah * 16;

  // A LDS write offsets (ushort units): [s][c=2*ah+q][arow][8]
  int awr[3][2];
#pragma unroll
  for (int s = 0; s < 3; ++s)
#pragma unroll
    for (int q = 0; q < 2; ++q)
      awr[s][q] = ((s * 4 + 2 * ah + q) * 128 + arow) * 8;

  const int fr = lane & 15;
  const int kc = lane >> 4;

  floatx4 acc[4][4], accS[4][4];
#pragma unroll
  for (int i = 0; i < 4; ++i)
#pragma unroll
    for (int j = 0; j < 4; ++j) { acc[i][j] = (floatx4)0.f; accS[i][j] = (floatx4)0.f; }

  float4 pa0[4], pa1[4];

  // B DMA: 24 instr/block/tile, 6 per wave: j = w + 4*jj
#define ISSUE_B(TILE, BUF)                                                        \
  {                                                                               \
    const long gt_ = (long)z * KT + (TILE);                                       \
    _Pragma("unroll")                                                             \
    for (int jj = 0; jj < 6; ++jj) {                                              \
      const int j_ = w + 4 * jj;                                                  \
      const int s_ = j_ >> 3, c_ = (j_ >> 1) & 3, i_ = j_ & 1;                    \
      const unsigned short* g_ = Bg + (long)s_ * NM_ +                            \
          ((gt_ * 4 + c_) * 256 + n0 + i_ * 64 + lane) * 8;                       \
      gload_lds16(g_, &Bs[BUF][((s_ * 4 + c_) * 128 + i_ * 64) * 8]);             \
    }                                                                             \
  }

#define BODY(TT, PAW, PAL, RBUF, DBUF)                                            \
  {                                                                               \
    __syncthreads();  /* drains DMA(TT)+A(TT); closes compute(TT-1) */            \
    ISSUE_B(((TT) + 1) & (KT - 1), DBUF);                                         \
    /* ds_write A(TT) splits from PAW */                                          \
    {                                                                             \
      unsigned q1[8], q2[8], q3[8];                                               \
      _Pragma("unroll")                                                           \
      for (int p = 0; p < 8; ++p) {                                               \
        float x0 = (&PAW[p >> 1].x)[(2 * p) & 3];                                 \
        float x1 = (&PAW[p >> 1].x)[(2 * p + 1) & 3];                             \
        split3_pair(x0, x1, q1[p], q2[p], q3[p]);                                 \
      }                                                                           \
      *(uint4*)&As[awr[0][0]] = make_uint4(q1[0], q1[1], q1[2], q1[3]);           \
      *(uint4*)&As[awr[0][1]] = make_uint4(q1[4], q1[5], q1[6], q1[7]);           \
      *(uint4*)&As[awr[1][0]] = make_uint4(q2[0], q2[1], q2[2], q2[3]);           \
      *(uint4*)&As[awr[1][1]] = make_uint4(q2[4], q2[5], q2[6], q2[7]);           \
      *(uint4*)&As[awr[2][0]] = make_uint4(q3[0], q3[1], q3[2], q3[3]);           \
      *(uint4*)&As[awr[2][1]] = make_uint4(q3[4], q3[5], q3[6], q3[7]);           \
    }                                                                             \
    /* prefetch A(TT+1) */                                                        \
    {                                                                             \
      const long ko_ = (long)(((TT) + 1) & (KT - 1)) * 32;                        \
      _Pragma("unroll")                                                           \
      for (int i = 0; i < 4; ++i) PAL[i] = *(const float4*)(Ag + ko_ + i * 4);    \
    }                                                                             \
    asm volatile("s_waitcnt lgkmcnt(0)" ::: "memory");                            \
    __builtin_amdgcn_s_barrier();                                                 \
    __builtin_amdgcn_sched_barrier(0);                                            \
    /* compute tile TT from As + Bs[RBUF] */                                      \
    {                                                                             \
      short8v af[3][4], bf[3][4];                                                 \
      _Pragma("unroll")                                                           \
      for (int f = 0; f < 4; ++f) {                                               \
        const int ar_ = (wm * 64 + f * 16 + fr) * 8;                              \
        const int br_ = (wn * 64 + f * 16 + fr) * 8;                              \
        _Pragma("unroll")                                                         \
        for (int s = 0; s < 3; ++s) {                                             \
          af[s][f] = *(const short8v*)&As[(s * 4 + kc) * 1024 + ar_];             \
          bf[s][f] = *(const short8v*)&Bs[RBUF][(s * 4 + kc) * 1024 + br_];       \
        }                                                                         \
      }                                                                           \
      _Pragma("unroll")                                                           \
      for (int fm = 0; fm < 4; ++fm) {                                            \
        _Pragma("unroll")                                                         \
        for (int fn = 0; fn < 4; ++fn) {                                          \
          floatx4 d = acc[fm][fn];                                                \
          d = __builtin_amdgcn_mfma_f32_16x16x32_bf16(af[0][fm], bf[0][fn], d, 0, 0, 0); \
          d = __builtin_amdgcn_mfma_f32_16x16x32_bf16(af[0][fm], bf[1][fn], d, 0, 0, 0); \
          d = __builtin_amdgcn_mfma_f32_16x16x32_bf16(af[1][fm], bf[0][fn], d, 0, 0, 0); \
          d = __builtin_amdgcn_mfma_f32_16x16x32_bf16(af[1][fm], bf[1][fn], d, 0, 0, 0); \
          d = __builtin_amdgcn_mfma_f32_16x16x32_bf16(af[0][fm], bf[2][fn], d, 0, 0, 0); \
          d = __builtin_amdgcn_mfma_f32_16x16x32_bf16(af[2][fm], bf[0][fn], d, 0, 0, 0); \
          acc[fm][fn] = d;                                                        \
        }                                                                         \
      }                                                                           \
    }                                                                             \
    /* chunked accumulation: flush every 32 tiles (numerics) */                   \
    if (((TT) & 31) == 31) {                                                      \
      _Pragma("unroll")                                                           \
      for (int i = 0; i < 4; ++i)                                                 \
        _Pragma("unroll")                                                         \
        for (int j = 0; j < 4; ++j) { accS[i][j] += acc[i][j]; acc[i][j] = (floatx4)0.f; } \
    }                                                                             \
  }

  // prologue: A(0) -> pa0, B(0) -> buf0
#pragma unroll
  for (int i = 0; i < 4; ++i) pa0[i] = *(const float4*)(Ag + i * 4);
  ISSUE_B(0, 0);

  for (int t = 0; t < KT; t += 2) {
    BODY(t,     pa0, pa1, 0, 1);
    BODY(t + 1, pa1, pa0, 1, 0);
  }

  // epilogue: C/D layout col=lane&15, row=(lane>>4)*4+j
#pragma unroll
  for (int fm = 0; fm < 4; ++fm) {
#pragma unroll
    for (int fn = 0; fn < 4; ++fn) {
      const long col  = n0 + wn * 64 + fn * 16 + fr;
      const long rowb = m0 + wm * 64 + fm * 16 + (lane >> 4) * 4;
#pragma unroll
      for (int j = 0; j < 4; ++j)
        Cp[(rowb + j) * 256 + col] = accS[fm][fn][j];
    }
  }
#undef BODY
#undef ISSUE_B
}

// ---------------- P1 += P0 ----------------
__global__ __launch_bounds__(256)
void reduce_add(const float* __restrict__ P0, float* __restrict__ P1, long n4)
{
  long i = (long)blockIdx.x * 256 + threadIdx.x;
  const long stride = (long)gridDim.x * 256;
  for (; i < n4; i += stride) {
    float4 a = ((const float4*)P0)[i];
    float4 b = ((const float4*)P1)[i];
    b.x += a.x; b.y += a.y; b.z += a.z; b.w += a.w;
    ((float4*)P1)[i] = b;
  }
}

// ---------------- edge scoring ----------------
__global__ __launch_bounds__(256)
void edge_score(const float* __restrict__ Z, const float* __restrict__ w2,
                const int* __restrict__ te, const int* __restrict__ fe,
                int E, float* __restrict__ out)
{
  const long gtid = (long)blockIdx.x * 256 + threadIdx.x;
  const long wid = gtid >> 6;
  const int lane = threadIdx.x & 63;
  if (wid >= 2L * E) return;
  const int* ep = (wid < E) ? (te + 2 * wid) : (fe + 2 * (wid - E));
  const int src = ep[0];
  const int dst = ep[1];
  const float4 a = ((const float4*)(Z + (long)src * 256))[lane];
  const float4 b = ((const float4*)(Z + (long)dst * 256))[lane];
  const float4 w = ((const float4*)w2)[lane];
  float s = a.x * b.x * w.x + a.y * b.y * w.y + a.z * b.z * w.z + a.w * b.w * w.w;
#pragma unroll
  for (int off = 32; off > 0; off >>= 1) s += __shfl_down(s, off);
  if (lane == 0) out[wid] = 1.0f / (1.0f + expf(-s));
}

extern "C" void kernel_launch(void* const* d_in, const int* in_sizes, int n_in,
                              void* d_out, int out_size, void* d_ws, size_t ws_size,
                              hipStream_t stream)
{
  const float* X   = (const float*)d_in[0];
  const float* adj = (const float*)d_in[1];
  const float* W   = (const float*)d_in[2];
  const float* W2  = (const float*)d_in[3];
  const int*   te  = (const int*)d_in[4];
  const int*   fe  = (const int*)d_in[5];

  const int E = in_sizes[4] / 2;

  float* ws = (float*)d_ws;
  float* XW = ws;                    // dead after transpose_split; reused as P0
  float* P0 = ws;
  float* P1 = ws + NM_;              // final Z lives here
  unsigned short* X1 = (unsigned short*)(ws + 2 * NM_);
  // X2/X3 at stride NM_ after X1 (gemm_split3 indexes Bg + s*NM_)
  unsigned short* X2 = X1 + NM_;
  unsigned short* X3 = X2 + NM_;
  // total ws use: 2*NM*4 + 3*NM*2 = 58.7 MB

  dim3 blk(256);
  gemm_f32_nn<<<dim3(128, 2), blk, 0, stream>>>(X, W, XW, 16384, 256, 512);
  transpose_split<<<dim3(256, 4), blk, 0, stream>>>(XW, X1, X2, X3);
  gemm_split3<<<dim3(128, 2, 2), blk, 0, stream>>>(adj, X1, P0, P1);
  reduce_add<<<dim3(2048), blk, 0, stream>>>(P0, P1, NM_ / 4);
  const long nwaves = 2L * E;
  const int nblocks = (int)((nwaves + 3) / 4);
  edge_score<<<dim3(nblocks), blk, 0, stream>>>(P1, W2, te, fe, E, (float*)d_out);
}

// Round 5
// 876.532 us; speedup vs baseline: 2.8114x; 1.0655x over previous
//
#include <hip/hip_runtime.h>
#include <math.h>

// N=16384, IN=512, HID=256, E=262144.
// Z = adj @ (X@W) via fp16 split-2 MFMA: a=a1+a2, b=b1+b2 (RNE fp16, exact
// residuals in f32), products a1b1+a1b2+a2b1 (dropped a2b2 ~2^-23 rel).
// Conflict-free chunk-major LDS, global_load_lds DMA for B (pre-tiled),
// raw-barrier pipeline, chunked accumulation for fp32-rounding control.

typedef __attribute__((ext_vector_type(8))) short short8v;
typedef _Float16 half8v __attribute__((ext_vector_type(8)));
typedef __attribute__((ext_vector_type(4))) float floatx4;

#define NM_ (16384L * 256L)
#define KT 256   // 32-wide k-tiles per split-K half (8192 k)

static __device__ __forceinline__ void split2_pair_f16(float x0, float x1,
                                                       unsigned& q1, unsigned& q2) {
  _Float16 h0 = (_Float16)x0, h1 = (_Float16)x1;     // RNE v_cvt_f16_f32
  float r0 = x0 - (float)h0, r1 = x1 - (float)h1;    // exact in f32
  _Float16 g0 = (_Float16)r0, g1 = (_Float16)r1;
  q1 = ((unsigned)__builtin_bit_cast(unsigned short, h1) << 16) |
       __builtin_bit_cast(unsigned short, h0);
  q2 = ((unsigned)__builtin_bit_cast(unsigned short, g1) << 16) |
       __builtin_bit_cast(unsigned short, g0);
}

static __device__ __forceinline__ void gload_lds16(const void* g, void* l) {
  __builtin_amdgcn_global_load_lds(
      (const __attribute__((address_space(1))) unsigned*)g,
      (__attribute__((address_space(3))) unsigned*)l, 16, 0, 0);
}

// ---------------- GEMM1: fp32 hierarchical (X @ W -> XW) ----------------
#define BM 128
#define BN 128
#define BK 16
#define LDAS (BM + 4)
#define LDBS (BN + 4)

__global__ __launch_bounds__(256, 1)
void gemm_f32_nn(const float* __restrict__ A, const float* __restrict__ B,
                 float* __restrict__ C, int M, int N, int K)
{
  __shared__ float As[2][BK][LDAS];
  __shared__ float Bs[2][BK][LDBS];

  const int tid = threadIdx.x;
  const int tx = tid & 15;
  const int ty = tid >> 4;
  const long m0 = (long)blockIdx.x * BM;
  const long n0 = (long)blockIdx.y * BN;

  const int a_row = tid >> 2;
  const int a_kc  = (tid & 3) << 2;
  const int b_row = tid >> 5;
  const int b_col = (tid & 31) << 2;

  const float* Ag0 = A + (m0 + a_row) * (long)K + a_kc;
  const float* Ag1 = A + (m0 + 64 + a_row) * (long)K + a_kc;
  const float* Bg0 = B + (long)b_row * N + n0 + b_col;
  const float* Bg1 = B + (long)(b_row + 8) * N + n0 + b_col;

  float4 av0 = *(const float4*)(Ag0);
  float4 av1 = *(const float4*)(Ag1);
  float4 bv0 = *(const float4*)(Bg0);
  float4 bv1 = *(const float4*)(Bg1);

  float acc[8][8];
#pragma unroll
  for (int i = 0; i < 8; ++i)
#pragma unroll
    for (int j = 0; j < 8; ++j) acc[i][j] = 0.f;

  const int nt = K / BK;
  int buf = 0;

#pragma unroll
  for (int i = 0; i < 4; ++i) {
    As[0][a_kc + i][a_row]      = (&av0.x)[i];
    As[0][a_kc + i][a_row + 64] = (&av1.x)[i];
  }
  *(float4*)&Bs[0][b_row][b_col]     = bv0;
  *(float4*)&Bs[0][b_row + 8][b_col] = bv1;
  __syncthreads();

  for (int t = 0; t < nt; ++t) {
    if (t + 1 < nt) {
      const long ko = (long)(t + 1) * BK;
      av0 = *(const float4*)(Ag0 + ko);
      av1 = *(const float4*)(Ag1 + ko);
      bv0 = *(const float4*)(Bg0 + ko * N);
      bv1 = *(const float4*)(Bg1 + ko * N);
    }
    float tacc[8][8];
#pragma unroll
    for (int i = 0; i < 8; ++i)
#pragma unroll
      for (int j = 0; j < 8; ++j) tacc[i][j] = 0.f;

#pragma unroll
    for (int kk = 0; kk < BK; ++kk) {
      float4 aA = *(const float4*)&As[buf][kk][ty * 4];
      float4 aB = *(const float4*)&As[buf][kk][ty * 4 + 64];
      float4 bA = *(const float4*)&Bs[buf][kk][tx * 4];
      float4 bB = *(const float4*)&Bs[buf][kk][tx * 4 + 64];
      const float ar[8] = {aA.x, aA.y, aA.z, aA.w, aB.x, aB.y, aB.z, aB.w};
      const float br[8] = {bA.x, bA.y, bA.z, bA.w, bB.x, bB.y, bB.z, bB.w};
#pragma unroll
      for (int i = 0; i < 8; ++i)
#pragma unroll
        for (int j = 0; j < 8; ++j)
          tacc[i][j] = fmaf(ar[i], br[j], tacc[i][j]);
    }
#pragma unroll
    for (int i = 0; i < 8; ++i)
#pragma unroll
      for (int j = 0; j < 8; ++j) acc[i][j] += tacc[i][j];

    if (t + 1 < nt) {
      const int nb = buf ^ 1;
#pragma unroll
      for (int i = 0; i < 4; ++i) {
        As[nb][a_kc + i][a_row]      = (&av0.x)[i];
        As[nb][a_kc + i][a_row + 64] = (&av1.x)[i];
      }
      *(float4*)&Bs[nb][b_row][b_col]     = bv0;
      *(float4*)&Bs[nb][b_row + 8][b_col] = bv1;
    }
    __syncthreads();
    buf ^= 1;
  }

#pragma unroll
  for (int i = 0; i < 8; ++i) {
    const long row = m0 + (i < 4 ? ty * 4 + i : 64 + ty * 4 + (i - 4));
#pragma unroll
    for (int c = 0; c < 2; ++c) {
      float4 v;
      v.x = acc[i][c * 4 + 0];
      v.y = acc[i][c * 4 + 1];
      v.z = acc[i][c * 4 + 2];
      v.w = acc[i][c * 4 + 3];
      *(float4*)&C[row * N + n0 + tx * 4 + c * 64] = v;
    }
  }
}

// ---- transpose + split2 XW -> DMA-ready tiles: [split][kt][c(4)][n(256)][8] ----
__global__ __launch_bounds__(256)
void transpose_split(const float* __restrict__ XW,
                     unsigned short* __restrict__ X1,
                     unsigned short* __restrict__ X2)
{
  __shared__ float T[64][65];
  const int tid = threadIdx.x;
  const long kb = (long)blockIdx.x * 64;   // XW row (k) tile
  const long nb = (long)blockIdx.y * 64;   // XW col (n) tile

#pragma unroll
  for (int i = 0; i < 4; ++i) {
    int idx = tid + 256 * i;
    int r = idx >> 4, c4 = (idx & 15) * 4;
    float4 v = *(const float4*)&XW[(kb + r) * 256 + nb + c4];
    T[r][c4 + 0] = v.x; T[r][c4 + 1] = v.y; T[r][c4 + 2] = v.z; T[r][c4 + 3] = v.w;
  }
  __syncthreads();

#pragma unroll
  for (int i = 0; i < 2; ++i) {
    int idx = tid + 256 * i;
    int n = idx >> 3, kq = (idx & 7) * 8;   // 8 consecutive k for column nb+n
    float x[8];
#pragma unroll
    for (int j = 0; j < 8; ++j) x[j] = T[kq + j][n];
    unsigned q1[4], q2[4];
#pragma unroll
    for (int p = 0; p < 4; ++p)
      split2_pair_f16(x[2 * p], x[2 * p + 1], q1[p], q2[p]);
    const long gk = kb + kq;
    const long gt = gk >> 5;                 // 32-wide k-tile
    const int  c  = (int)((gk >> 3) & 3);    // 16B chunk within tile
    const long o  = ((gt * 4 + c) * 256 + (nb + n)) * 8;
    *(uint4*)&X1[o] = make_uint4(q1[0], q1[1], q1[2], q1[3]);
    *(uint4*)&X2[o] = make_uint4(q2[0], q2[1], q2[2], q2[3]);
  }
}

// ---------------- GEMM2: Z = adj @ XW, fp16 split-2 MFMA ----------------
// LDS chunk-major: panel[s][c][row][8 halves]; all reads/writes 16-lane
// contiguous 16B => zero bank conflicts by construction.

__global__ __launch_bounds__(256, 3)
void gemm_split2(const float* __restrict__ A,
                 const unsigned short* __restrict__ Bg,   // 2 splits, stride NM_
                 float* __restrict__ P0, float* __restrict__ P1)
{
  __shared__ unsigned short As[8192];       // 2*4*128*8 = 16 KB
  __shared__ unsigned short Bs[2][8192];    // double-buffered, 32 KB

  const int tid  = threadIdx.x;
  const int lane = tid & 63;
  const int w    = tid >> 6;
  const int wm   = w >> 1, wn = w & 1;
  const long m0 = (long)blockIdx.x * 128;
  const long n0 = (long)blockIdx.y * 128;
  const int  z  = blockIdx.z;
  float* __restrict__ Cp = z ? P1 : P0;

  // A staging: thread -> (row = tid&127, k 16*ah..16*ah+15)
  const int arow = tid & 127;
  const int ah   = tid >> 7;
  const float* Ag = A + (m0 + arow) * 16384L + (long)z * 8192 + ah * 16;

  // A LDS write offsets (ushort units): [s][c=2*ah+q][arow][8]
  int awr[2][2];
#pragma unroll
  for (int s = 0; s < 2; ++s)
#pragma unroll
    for (int q = 0; q < 2; ++q)
      awr[s][q] = ((s * 4 + 2 * ah + q) * 128 + arow) * 8;

  const int fr = lane & 15;
  const int kc = lane >> 4;

  floatx4 acc[4][4], accS[4][4];
#pragma unroll
  for (int i = 0; i < 4; ++i)
#pragma unroll
    for (int j = 0; j < 4; ++j) { acc[i][j] = (floatx4)0.f; accS[i][j] = (floatx4)0.f; }

  float4 pa0[4], pa1[4];

  // B DMA: 16 instr/block/tile, 4 per wave: j = w + 4*jj
#define ISSUE_B(TILE, BUF)                                                        \
  {                                                                               \
    const long gt_ = (long)z * KT + (TILE);                                       \
    _Pragma("unroll")                                                             \
    for (int jj = 0; jj < 4; ++jj) {                                              \
      const int j_ = w + 4 * jj;                                                  \
      const int s_ = j_ >> 3, c_ = (j_ >> 1) & 3, i_ = j_ & 1;                    \
      const unsigned short* g_ = Bg + (long)s_ * NM_ +                            \
          ((gt_ * 4 + c_) * 256 + n0 + i_ * 64 + lane) * 8;                       \
      gload_lds16(g_, &Bs[BUF][((s_ * 4 + c_) * 128 + i_ * 64) * 8]);             \
    }                                                                             \
  }

#define BODY(TT, PAW, PAL, RBUF, DBUF)                                            \
  {                                                                               \
    __syncthreads();  /* drains DMA(TT)+A(TT); closes compute(TT-1) */            \
    ISSUE_B(((TT) + 1) & (KT - 1), DBUF);                                         \
    /* ds_write A(TT) splits from PAW */                                          \
    {                                                                             \
      unsigned q1[8], q2[8];                                                      \
      _Pragma("unroll")                                                           \
      for (int p = 0; p < 8; ++p) {                                               \
        float x0 = (&PAW[p >> 1].x)[(2 * p) & 3];                                 \
        float x1 = (&PAW[p >> 1].x)[(2 * p + 1) & 3];                             \
        split2_pair_f16(x0, x1, q1[p], q2[p]);                                    \
      }                                                                           \
      *(uint4*)&As[awr[0][0]] = make_uint4(q1[0], q1[1], q1[2], q1[3]);           \
      *(uint4*)&As[awr[0][1]] = make_uint4(q1[4], q1[5], q1[6], q1[7]);           \
      *(uint4*)&As[awr[1][0]] = make_uint4(q2[0], q2[1], q2[2], q2[3]);           \
      *(uint4*)&As[awr[1][1]] = make_uint4(q2[4], q2[5], q2[6], q2[7]);           \
    }                                                                             \
    /* prefetch A(TT+1) */                                                        \
    {                                                                             \
      const long ko_ = (long)(((TT) + 1) & (KT - 1)) * 32;                        \
      _Pragma("unroll")                                                           \
      for (int i = 0; i < 4; ++i) PAL[i] = *(const float4*)(Ag + ko_ + i * 4);    \
    }                                                                             \
    asm volatile("s_waitcnt lgkmcnt(0)" ::: "memory");                            \
    __builtin_amdgcn_s_barrier();                                                 \
    __builtin_amdgcn_sched_barrier(0);                                            \
    /* compute tile TT from As + Bs[RBUF] */                                      \
    {                                                                             \
      half8v af[2][4], bf[2][4];                                                  \
      _Pragma("unroll")                                                           \
      for (int f = 0; f < 4; ++f) {                                               \
        const int ar_ = (wm * 64 + f * 16 + fr) * 8;                              \
        const int br_ = (wn * 64 + f * 16 + fr) * 8;                              \
        _Pragma("unroll")                                                         \
        for (int s = 0; s < 2; ++s) {                                             \
          af[s][f] = *(const half8v*)&As[(s * 4 + kc) * 1024 + ar_];              \
          bf[s][f] = *(const half8v*)&Bs[RBUF][(s * 4 + kc) * 1024 + br_];        \
        }                                                                         \
      }                                                                           \
      _Pragma("unroll")                                                           \
      for (int fm = 0; fm < 4; ++fm) {                                            \
        _Pragma("unroll")                                                         \
        for (int fn = 0; fn < 4; ++fn) {                                          \
          floatx4 d = acc[fm][fn];                                                \
          d = __builtin_amdgcn_mfma_f32_16x16x32_f16(af[0][fm], bf[0][fn], d, 0, 0, 0); \
          d = __builtin_amdgcn_mfma_f32_16x16x32_f16(af[0][fm], bf[1][fn], d, 0, 0, 0); \
          d = __builtin_amdgcn_mfma_f32_16x16x32_f16(af[1][fm], bf[0][fn], d, 0, 0, 0); \
          acc[fm][fn] = d;                                                        \
        }                                                                         \
      }                                                                           \
    }                                                                             \
    /* chunked accumulation: flush every 32 tiles (numerics) */                   \
    if (((TT) & 31) == 31) {                                                      \
      _Pragma("unroll")                                                           \
      for (int i = 0; i < 4; ++i)                                                 \
        _Pragma("unroll")                                                         \
        for (int j = 0; j < 4; ++j) { accS[i][j] += acc[i][j]; acc[i][j] = (floatx4)0.f; } \
    }                                                                             \
  }

  // prologue: A(0) -> pa0, B(0) -> buf0
#pragma unroll
  for (int i = 0; i < 4; ++i) pa0[i] = *(const float4*)(Ag + i * 4);
  ISSUE_B(0, 0);

  for (int t = 0; t < KT; t += 2) {
    BODY(t,     pa0, pa1, 0, 1);
    BODY(t + 1, pa1, pa0, 1, 0);
  }

  // epilogue: C/D layout col=lane&15, row=(lane>>4)*4+j
#pragma unroll
  for (int fm = 0; fm < 4; ++fm) {
#pragma unroll
    for (int fn = 0; fn < 4; ++fn) {
      const long col  = n0 + wn * 64 + fn * 16 + fr;
      const long rowb = m0 + wm * 64 + fm * 16 + (lane >> 4) * 4;
#pragma unroll
      for (int j = 0; j < 4; ++j)
        Cp[(rowb + j) * 256 + col] = accS[fm][fn][j];
    }
  }
#undef BODY
#undef ISSUE_B
}

// ---------------- P1 += P0 ----------------
__global__ __launch_bounds__(256)
void reduce_add(const float* __restrict__ P0, float* __restrict__ P1, long n4)
{
  long i = (long)blockIdx.x * 256 + threadIdx.x;
  const long stride = (long)gridDim.x * 256;
  for (; i < n4; i += stride) {
    float4 a = ((const float4*)P0)[i];
    float4 b = ((const float4*)P1)[i];
    b.x += a.x; b.y += a.y; b.z += a.z; b.w += a.w;
    ((float4*)P1)[i] = b;
  }
}

// ---------------- edge scoring ----------------
__global__ __launch_bounds__(256)
void edge_score(const float* __restrict__ Z, const float* __restrict__ w2,
                const int* __restrict__ te, const int* __restrict__ fe,
                int E, float* __restrict__ out)
{
  const long gtid = (long)blockIdx.x * 256 + threadIdx.x;
  const long wid = gtid >> 6;
  const int lane = threadIdx.x & 63;
  if (wid >= 2L * E) return;
  const int* ep = (wid < E) ? (te + 2 * wid) : (fe + 2 * (wid - E));
  const int src = ep[0];
  const int dst = ep[1];
  const float4 a = ((const float4*)(Z + (long)src * 256))[lane];
  const float4 b = ((const float4*)(Z + (long)dst * 256))[lane];
  const float4 w = ((const float4*)w2)[lane];
  float s = a.x * b.x * w.x + a.y * b.y * w.y + a.z * b.z * w.z + a.w * b.w * w.w;
#pragma unroll
  for (int off = 32; off > 0; off >>= 1) s += __shfl_down(s, off);
  if (lane == 0) out[wid] = 1.0f / (1.0f + expf(-s));
}

extern "C" void kernel_launch(void* const* d_in, const int* in_sizes, int n_in,
                              void* d_out, int out_size, void* d_ws, size_t ws_size,
                              hipStream_t stream)
{
  const float* X   = (const float*)d_in[0];
  const float* adj = (const float*)d_in[1];
  const float* W   = (const float*)d_in[2];
  const float* W2  = (const float*)d_in[3];
  const int*   te  = (const int*)d_in[4];
  const int*   fe  = (const int*)d_in[5];

  const int E = in_sizes[4] / 2;

  float* ws = (float*)d_ws;
  float* XW = ws;                    // dead after transpose_split; reused as P0
  float* P0 = ws;
  float* P1 = ws + NM_;              // final Z lives here
  unsigned short* X1 = (unsigned short*)(ws + 2 * NM_);
  unsigned short* X2 = X1 + NM_;     // gemm_split2 indexes Bg + s*NM_
  // total ws use: 2*NM*4 + 2*NM*2 = 50.3 MB

  dim3 blk(256);
  gemm_f32_nn<<<dim3(128, 2), blk, 0, stream>>>(X, W, XW, 16384, 256, 512);
  transpose_split<<<dim3(256, 4), blk, 0, stream>>>(XW, X1, X2);
  gemm_split2<<<dim3(128, 2, 2), blk, 0, stream>>>(adj, X1, P0, P1);
  reduce_add<<<dim3(2048), blk, 0, stream>>>(P0, P1, NM_ / 4);
  const long nwaves = 2L * E;
  const int nblocks = (int)((nwaves + 3) / 4);
  edge_score<<<dim3(nblocks), blk, 0, stream>>>(P1, W2, te, fe, E, (float*)d_out);
}

// Round 6
// 828.828 us; speedup vs baseline: 2.9732x; 1.0576x over previous
//
#include <hip/hip_runtime.h>
#include <math.h>

// N=16384, IN=512, HID=256, E=262144.
// Z = adj @ (X@W) via fp16 split-2 MFMA: a=a1+a2, b=b1+b2 (RNE fp16, exact
// residuals in f32), products a1b1+a1b2+a2b1 (dropped a2b2 ~2^-23 rel).
// R5: single-barrier pipeline, counted vmcnt (never 0 in loop), As+Bs both
// double-buffered, A-prefetch distance 2, XCD-aware block swizzle.

typedef _Float16 half8v __attribute__((ext_vector_type(8)));
typedef __attribute__((ext_vector_type(4))) float floatx4;

#define NM_ (16384L * 256L)
#define KT 256   // 32-wide k-tiles per split-K half (8192 k)

static __device__ __forceinline__ void split2_pair_f16(float x0, float x1,
                                                       unsigned& q1, unsigned& q2) {
  _Float16 h0 = (_Float16)x0, h1 = (_Float16)x1;     // RNE v_cvt_f16_f32
  float r0 = x0 - (float)h0, r1 = x1 - (float)h1;    // exact in f32
  _Float16 g0 = (_Float16)r0, g1 = (_Float16)r1;
  q1 = ((unsigned)__builtin_bit_cast(unsigned short, h1) << 16) |
       __builtin_bit_cast(unsigned short, h0);
  q2 = ((unsigned)__builtin_bit_cast(unsigned short, g1) << 16) |
       __builtin_bit_cast(unsigned short, g0);
}

static __device__ __forceinline__ void gload_lds16(const void* g, void* l) {
  __builtin_amdgcn_global_load_lds(
      (const __attribute__((address_space(1))) unsigned*)g,
      (__attribute__((address_space(3))) unsigned*)l, 16, 0, 0);
}

// ---------------- GEMM1: fp32 hierarchical (X @ W -> XW) ----------------
#define BM 128
#define BN 128
#define BK 16
#define LDAS (BM + 4)
#define LDBS (BN + 4)

__global__ __launch_bounds__(256, 1)
void gemm_f32_nn(const float* __restrict__ A, const float* __restrict__ B,
                 float* __restrict__ C, int M, int N, int K)
{
  __shared__ float As[2][BK][LDAS];
  __shared__ float Bs[2][BK][LDBS];

  const int tid = threadIdx.x;
  const int tx = tid & 15;
  const int ty = tid >> 4;
  const long m0 = (long)blockIdx.x * BM;
  const long n0 = (long)blockIdx.y * BN;

  const int a_row = tid >> 2;
  const int a_kc  = (tid & 3) << 2;
  const int b_row = tid >> 5;
  const int b_col = (tid & 31) << 2;

  const float* Ag0 = A + (m0 + a_row) * (long)K + a_kc;
  const float* Ag1 = A + (m0 + 64 + a_row) * (long)K + a_kc;
  const float* Bg0 = B + (long)b_row * N + n0 + b_col;
  const float* Bg1 = B + (long)(b_row + 8) * N + n0 + b_col;

  float4 av0 = *(const float4*)(Ag0);
  float4 av1 = *(const float4*)(Ag1);
  float4 bv0 = *(const float4*)(Bg0);
  float4 bv1 = *(const float4*)(Bg1);

  float acc[8][8];
#pragma unroll
  for (int i = 0; i < 8; ++i)
#pragma unroll
    for (int j = 0; j < 8; ++j) acc[i][j] = 0.f;

  const int nt = K / BK;
  int buf = 0;

#pragma unroll
  for (int i = 0; i < 4; ++i) {
    As[0][a_kc + i][a_row]      = (&av0.x)[i];
    As[0][a_kc + i][a_row + 64] = (&av1.x)[i];
  }
  *(float4*)&Bs[0][b_row][b_col]     = bv0;
  *(float4*)&Bs[0][b_row + 8][b_col] = bv1;
  __syncthreads();

  for (int t = 0; t < nt; ++t) {
    if (t + 1 < nt) {
      const long ko = (long)(t + 1) * BK;
      av0 = *(const float4*)(Ag0 + ko);
      av1 = *(const float4*)(Ag1 + ko);
      bv0 = *(const float4*)(Bg0 + ko * N);
      bv1 = *(const float4*)(Bg1 + ko * N);
    }
    float tacc[8][8];
#pragma unroll
    for (int i = 0; i < 8; ++i)
#pragma unroll
      for (int j = 0; j < 8; ++j) tacc[i][j] = 0.f;

#pragma unroll
    for (int kk = 0; kk < BK; ++kk) {
      float4 aA = *(const float4*)&As[buf][kk][ty * 4];
      float4 aB = *(const float4*)&As[buf][kk][ty * 4 + 64];
      float4 bA = *(const float4*)&Bs[buf][kk][tx * 4];
      float4 bB = *(const float4*)&Bs[buf][kk][tx * 4 + 64];
      const float ar[8] = {aA.x, aA.y, aA.z, aA.w, aB.x, aB.y, aB.z, aB.w};
      const float br[8] = {bA.x, bA.y, bA.z, bA.w, bB.x, bB.y, bB.z, bB.w};
#pragma unroll
      for (int i = 0; i < 8; ++i)
#pragma unroll
        for (int j = 0; j < 8; ++j)
          tacc[i][j] = fmaf(ar[i], br[j], tacc[i][j]);
    }
#pragma unroll
    for (int i = 0; i < 8; ++i)
#pragma unroll
      for (int j = 0; j < 8; ++j) acc[i][j] += tacc[i][j];

    if (t + 1 < nt) {
      const int nb = buf ^ 1;
#pragma unroll
      for (int i = 0; i < 4; ++i) {
        As[nb][a_kc + i][a_row]      = (&av0.x)[i];
        As[nb][a_kc + i][a_row + 64] = (&av1.x)[i];
      }
      *(float4*)&Bs[nb][b_row][b_col]     = bv0;
      *(float4*)&Bs[nb][b_row + 8][b_col] = bv1;
    }
    __syncthreads();
    buf ^= 1;
  }

#pragma unroll
  for (int i = 0; i < 8; ++i) {
    const long row = m0 + (i < 4 ? ty * 4 + i : 64 + ty * 4 + (i - 4));
#pragma unroll
    for (int c = 0; c < 2; ++c) {
      float4 v;
      v.x = acc[i][c * 4 + 0];
      v.y = acc[i][c * 4 + 1];
      v.z = acc[i][c * 4 + 2];
      v.w = acc[i][c * 4 + 3];
      *(float4*)&C[row * N + n0 + tx * 4 + c * 64] = v;
    }
  }
}

// ---- transpose + split2 XW -> DMA-ready tiles: [split][kt][c(4)][n(256)][8] ----
__global__ __launch_bounds__(256)
void transpose_split(const float* __restrict__ XW,
                     unsigned short* __restrict__ X1,
                     unsigned short* __restrict__ X2)
{
  __shared__ float T[64][65];
  const int tid = threadIdx.x;
  const long kb = (long)blockIdx.x * 64;   // XW row (k) tile
  const long nb = (long)blockIdx.y * 64;   // XW col (n) tile

#pragma unroll
  for (int i = 0; i < 4; ++i) {
    int idx = tid + 256 * i;
    int r = idx >> 4, c4 = (idx & 15) * 4;
    float4 v = *(const float4*)&XW[(kb + r) * 256 + nb + c4];
    T[r][c4 + 0] = v.x; T[r][c4 + 1] = v.y; T[r][c4 + 2] = v.z; T[r][c4 + 3] = v.w;
  }
  __syncthreads();

#pragma unroll
  for (int i = 0; i < 2; ++i) {
    int idx = tid + 256 * i;
    int n = idx >> 3, kq = (idx & 7) * 8;   // 8 consecutive k for column nb+n
    float x[8];
#pragma unroll
    for (int j = 0; j < 8; ++j) x[j] = T[kq + j][n];
    unsigned q1[4], q2[4];
#pragma unroll
    for (int p = 0; p < 4; ++p)
      split2_pair_f16(x[2 * p], x[2 * p + 1], q1[p], q2[p]);
    const long gk = kb + kq;
    const long gt = gk >> 5;                 // 32-wide k-tile
    const int  c  = (int)((gk >> 3) & 3);    // 16B chunk within tile
    const long o  = ((gt * 4 + c) * 256 + (nb + n)) * 8;
    *(uint4*)&X1[o] = make_uint4(q1[0], q1[1], q1[2], q1[3]);
    *(uint4*)&X2[o] = make_uint4(q2[0], q2[1], q2[2], q2[3]);
  }
}

// ---------------- GEMM2: Z = adj @ XW, fp16 split-2 MFMA ----------------
// Single barrier/iter; split+DMA of tile k+1 overlap compute of tile k.
// vmcnt contract at BODY(TT) entry: DMA(TT) and Aload(TT+1) complete;
// outstanding = Aload(TT+2) only. Bottom wait vmcnt(4) re-establishes it.

__global__ __launch_bounds__(256, 2)
void gemm_split2(const float* __restrict__ A,
                 const unsigned short* __restrict__ Bg,   // 2 splits, stride NM_
                 float* __restrict__ P0, float* __restrict__ P1)
{
  __shared__ unsigned short As[2][8192];    // 2 x 16 KB
  __shared__ unsigned short Bs[2][8192];    // 2 x 16 KB

  const int tid  = threadIdx.x;
  const int lane = tid & 63;
  const int w    = tid >> 6;
  const int wm   = w >> 1, wn = w & 1;

  // XCD swizzle: 512 blocks = 8 XCDs x 64; both n-tiles of an (m,z) adj
  // panel land on the same XCD for L2 reuse.
  const int bid = blockIdx.x;
  const int swz = (bid & 7) * 64 + (bid >> 3);
  const long m0 = (long)(swz >> 2) * 128;
  const long n0 = (long)((swz >> 1) & 1) * 128;
  const int  z  = swz & 1;
  float* __restrict__ Cp = z ? P1 : P0;

  // A staging: thread -> (row = tid&127, k 16*ah..16*ah+15)
  const int arow = tid & 127;
  const int ah   = tid >> 7;
  const float* Ag = A + (m0 + arow) * 16384L + (long)z * 8192 + ah * 16;

  // A LDS write offsets (ushort units within one As buffer): [s][c=2*ah+q][arow][8]
  int awr[2][2];
#pragma unroll
  for (int s = 0; s < 2; ++s)
#pragma unroll
    for (int q = 0; q < 2; ++q)
      awr[s][q] = ((s * 4 + 2 * ah + q) * 128 + arow) * 8;

  const int fr = lane & 15;
  const int kc = lane >> 4;

  floatx4 acc[4][4], accS[4][4];
#pragma unroll
  for (int i = 0; i < 4; ++i)
#pragma unroll
    for (int j = 0; j < 4; ++j) { acc[i][j] = (floatx4)0.f; accS[i][j] = (floatx4)0.f; }

  float4 pa0[4], pa1[4];

  // B DMA: 16 instr/block/tile, 4 per wave: j = w + 4*jj
#define ISSUE_B(TILE, BUF)                                                        \
  {                                                                               \
    const long gt_ = (long)z * KT + (TILE);                                       \
    _Pragma("unroll")                                                             \
    for (int jj = 0; jj < 4; ++jj) {                                              \
      const int j_ = w + 4 * jj;                                                  \
      const int s_ = j_ >> 3, c_ = (j_ >> 1) & 3, i_ = j_ & 1;                    \
      const unsigned short* g_ = Bg + (long)s_ * NM_ +                            \
          ((gt_ * 4 + c_) * 256 + n0 + i_ * 64 + lane) * 8;                       \
      gload_lds16(g_, &Bs[BUF][((s_ * 4 + c_) * 128 + i_ * 64) * 8]);             \
    }                                                                             \
  }

#define SPLIT_WRITE(PAW, NB)                                                      \
  {                                                                               \
    unsigned q1[8], q2[8];                                                        \
    _Pragma("unroll")                                                             \
    for (int p = 0; p < 8; ++p) {                                                 \
      float x0 = (&PAW[p >> 1].x)[(2 * p) & 3];                                   \
      float x1 = (&PAW[p >> 1].x)[(2 * p + 1) & 3];                               \
      split2_pair_f16(x0, x1, q1[p], q2[p]);                                      \
    }                                                                             \
    *(uint4*)&As[NB][awr[0][0]] = make_uint4(q1[0], q1[1], q1[2], q1[3]);         \
    *(uint4*)&As[NB][awr[0][1]] = make_uint4(q1[4], q1[5], q1[6], q1[7]);         \
    *(uint4*)&As[NB][awr[1][0]] = make_uint4(q2[0], q2[1], q2[2], q2[3]);         \
    *(uint4*)&As[NB][awr[1][1]] = make_uint4(q2[4], q2[5], q2[6], q2[7]);         \
  }

  // BODY(TT): computes tile TT from buffers[CUR]; stages tile TT+1 into
  // buffers[CUR^1] (DMA + split of PAW=A(TT+1)); reloads PAW <- A(TT+3).
#define BODY(TT, PAW, CUR)                                                        \
  {                                                                               \
    ISSUE_B(((TT) + 1) & (KT - 1), (CUR) ^ 1);                                    \
    __builtin_amdgcn_sched_barrier(0);  /* pin DMA first in vm queue */           \
    SPLIT_WRITE(PAW, (CUR) ^ 1);                                                  \
    {                                                                             \
      const long ko_ = (long)(((TT) + 3) & (KT - 1)) * 32;                        \
      _Pragma("unroll")                                                           \
      for (int i = 0; i < 4; ++i) PAW[i] = *(const float4*)(Ag + ko_ + i * 4);    \
    }                                                                             \
    {                                                                             \
      half8v af[2][4], bf[2][4];                                                  \
      _Pragma("unroll")                                                           \
      for (int f = 0; f < 4; ++f) {                                               \
        const int ar_ = (wm * 64 + f * 16 + fr) * 8;                              \
        const int br_ = (wn * 64 + f * 16 + fr) * 8;                              \
        _Pragma("unroll")                                                         \
        for (int s = 0; s < 2; ++s) {                                             \
          af[s][f] = *(const half8v*)&As[CUR][(s * 4 + kc) * 1024 + ar_];         \
          bf[s][f] = *(const half8v*)&Bs[CUR][(s * 4 + kc) * 1024 + br_];         \
        }                                                                         \
      }                                                                           \
      _Pragma("unroll")                                                           \
      for (int fm = 0; fm < 4; ++fm) {                                            \
        _Pragma("unroll")                                                         \
        for (int fn = 0; fn < 4; ++fn) {                                          \
          floatx4 d = acc[fm][fn];                                                \
          d = __builtin_amdgcn_mfma_f32_16x16x32_f16(af[0][fm], bf[0][fn], d, 0, 0, 0); \
          d = __builtin_amdgcn_mfma_f32_16x16x32_f16(af[0][fm], bf[1][fn], d, 0, 0, 0); \
          d = __builtin_amdgcn_mfma_f32_16x16x32_f16(af[1][fm], bf[0][fn], d, 0, 0, 0); \
          acc[fm][fn] = d;                                                        \
        }                                                                         \
      }                                                                           \
    }                                                                             \
    if (((TT) & 31) == 31) {                                                      \
      _Pragma("unroll")                                                           \
      for (int i = 0; i < 4; ++i)                                                 \
        _Pragma("unroll")                                                         \
        for (int j = 0; j < 4; ++j) { accS[i][j] += acc[i][j]; acc[i][j] = (floatx4)0.f; } \
    }                                                                             \
    asm volatile("s_waitcnt vmcnt(4) lgkmcnt(0)" ::: "memory");                   \
    __builtin_amdgcn_s_barrier();                                                 \
    __builtin_amdgcn_sched_barrier(0);                                            \
  }

  // ---- prologue: As[0] <- split A(0); Bs[0] <- DMA B(0); pa0 <- A(1); pa1 <- A(2)
#pragma unroll
  for (int i = 0; i < 4; ++i) pa0[i] = *(const float4*)(Ag + i * 4);
  asm volatile("s_waitcnt vmcnt(0)" ::: "memory");
  SPLIT_WRITE(pa0, 0);
  ISSUE_B(0, 0);
  __builtin_amdgcn_sched_barrier(0);   // pin DMA before the pa reloads
#pragma unroll
  for (int i = 0; i < 4; ++i) pa0[i] = *(const float4*)(Ag + 32 + i * 4);
#pragma unroll
  for (int i = 0; i < 4; ++i) pa1[i] = *(const float4*)(Ag + 64 + i * 4);
  asm volatile("s_waitcnt vmcnt(4) lgkmcnt(0)" ::: "memory");
  __builtin_amdgcn_s_barrier();
  __builtin_amdgcn_sched_barrier(0);

  for (int t = 0; t < KT; t += 2) {
    BODY(t,     pa0, 0);
    BODY(t + 1, pa1, 1);
  }

  asm volatile("s_waitcnt vmcnt(0) lgkmcnt(0)" ::: "memory");

  // epilogue: C/D layout col=lane&15, row=(lane>>4)*4+j
#pragma unroll
  for (int fm = 0; fm < 4; ++fm) {
#pragma unroll
    for (int fn = 0; fn < 4; ++fn) {
      const long col  = n0 + wn * 64 + fn * 16 + fr;
      const long rowb = m0 + wm * 64 + fm * 16 + (lane >> 4) * 4;
#pragma unroll
      for (int j = 0; j < 4; ++j)
        Cp[(rowb + j) * 256 + col] = accS[fm][fn][j];
    }
  }
#undef BODY
#undef SPLIT_WRITE
#undef ISSUE_B
}

// ---------------- P1 += P0 ----------------
__global__ __launch_bounds__(256)
void reduce_add(const float* __restrict__ P0, float* __restrict__ P1, long n4)
{
  long i = (long)blockIdx.x * 256 + threadIdx.x;
  const long stride = (long)gridDim.x * 256;
  for (; i < n4; i += stride) {
    float4 a = ((const float4*)P0)[i];
    float4 b = ((const float4*)P1)[i];
    b.x += a.x; b.y += a.y; b.z += a.z; b.w += a.w;
    ((float4*)P1)[i] = b;
  }
}

// ---------------- edge scoring ----------------
__global__ __launch_bounds__(256)
void edge_score(const float* __restrict__ Z, const float* __restrict__ w2,
                const int* __restrict__ te, const int* __restrict__ fe,
                int E, float* __restrict__ out)
{
  const long gtid = (long)blockIdx.x * 256 + threadIdx.x;
  const long wid = gtid >> 6;
  const int lane = threadIdx.x & 63;
  if (wid >= 2L * E) return;
  const int* ep = (wid < E) ? (te + 2 * wid) : (fe + 2 * (wid - E));
  const int src = ep[0];
  const int dst = ep[1];
  const float4 a = ((const float4*)(Z + (long)src * 256))[lane];
  const float4 b = ((const float4*)(Z + (long)dst * 256))[lane];
  const float4 w = ((const float4*)w2)[lane];
  float s = a.x * b.x * w.x + a.y * b.y * w.y + a.z * b.z * w.z + a.w * b.w * w.w;
#pragma unroll
  for (int off = 32; off > 0; off >>= 1) s += __shfl_down(s, off);
  if (lane == 0) out[wid] = 1.0f / (1.0f + expf(-s));
}

extern "C" void kernel_launch(void* const* d_in, const int* in_sizes, int n_in,
                              void* d_out, int out_size, void* d_ws, size_t ws_size,
                              hipStream_t stream)
{
  const float* X   = (const float*)d_in[0];
  const float* adj = (const float*)d_in[1];
  const float* W   = (const float*)d_in[2];
  const float* W2  = (const float*)d_in[3];
  const int*   te  = (const int*)d_in[4];
  const int*   fe  = (const int*)d_in[5];

  const int E = in_sizes[4] / 2;

  float* ws = (float*)d_ws;
  float* XW = ws;                    // dead after transpose_split; reused as P0
  float* P0 = ws;
  float* P1 = ws + NM_;              // final Z lives here
  unsigned short* X1 = (unsigned short*)(ws + 2 * NM_);
  unsigned short* X2 = X1 + NM_;     // gemm_split2 indexes Bg + s*NM_
  // total ws use: 2*NM*4 + 2*NM*2 = 50.3 MB

  dim3 blk(256);
  gemm_f32_nn<<<dim3(128, 2), blk, 0, stream>>>(X, W, XW, 16384, 256, 512);
  transpose_split<<<dim3(256, 4), blk, 0, stream>>>(XW, X1, X2);
  gemm_split2<<<dim3(512), blk, 0, stream>>>(adj, X1, P0, P1);
  reduce_add<<<dim3(2048), blk, 0, stream>>>(P0, P1, NM_ / 4);
  const long nwaves = 2L * E;
  const int nblocks = (int)((nwaves + 3) / 4);
  edge_score<<<dim3(nblocks), blk, 0, stream>>>(P1, W2, te, fe, E, (float*)d_out);
}

// Round 7
// 767.205 us; speedup vs baseline: 3.2120x; 1.0803x over previous
//
#include <hip/hip_runtime.h>
#include <math.h>

// N=16384, IN=512, HID=256, E=262144.
// Z = adj @ (X@W) via fp16 split-2 MFMA: a=a1+a2, b=b1+b2 (RNE fp16, exact
// residuals in f32), products a1b1+a1b2+a2b1 (dropped a2b2 ~2^-22 rel).
// R6: B fragments load DIRECTLY global->VGPR (pre-formatted by
// transpose_split, L3-resident) -- B never touches LDS. LDS holds only the
// double-buffered A splits (32 KB/block). One raw barrier per iter,
// lgkmcnt-only (global loads stay in flight across it).

typedef _Float16 half8v __attribute__((ext_vector_type(8)));
typedef __attribute__((ext_vector_type(4))) float floatx4;

#define NM_ (16384L * 256L)
#define KT 256   // 32-wide k-tiles per split-K half (8192 k)

static __device__ __forceinline__ void split2_pair_f16(float x0, float x1,
                                                       unsigned& q1, unsigned& q2) {
  _Float16 h0 = (_Float16)x0, h1 = (_Float16)x1;     // RNE v_cvt_f16_f32
  float r0 = x0 - (float)h0, r1 = x1 - (float)h1;    // exact in f32
  _Float16 g0 = (_Float16)r0, g1 = (_Float16)r1;
  q1 = ((unsigned)__builtin_bit_cast(unsigned short, h1) << 16) |
       __builtin_bit_cast(unsigned short, h0);
  q2 = ((unsigned)__builtin_bit_cast(unsigned short, g1) << 16) |
       __builtin_bit_cast(unsigned short, g0);
}

// ---------------- GEMM1: fp32 hierarchical (X @ W -> XW) ----------------
#define BM 128
#define BN 128
#define BK 16
#define LDAS (BM + 4)
#define LDBS (BN + 4)

__global__ __launch_bounds__(256, 1)
void gemm_f32_nn(const float* __restrict__ A, const float* __restrict__ B,
                 float* __restrict__ C, int M, int N, int K)
{
  __shared__ float As[2][BK][LDAS];
  __shared__ float Bs[2][BK][LDBS];

  const int tid = threadIdx.x;
  const int tx = tid & 15;
  const int ty = tid >> 4;
  const long m0 = (long)blockIdx.x * BM;
  const long n0 = (long)blockIdx.y * BN;

  const int a_row = tid >> 2;
  const int a_kc  = (tid & 3) << 2;
  const int b_row = tid >> 5;
  const int b_col = (tid & 31) << 2;

  const float* Ag0 = A + (m0 + a_row) * (long)K + a_kc;
  const float* Ag1 = A + (m0 + 64 + a_row) * (long)K + a_kc;
  const float* Bg0 = B + (long)b_row * N + n0 + b_col;
  const float* Bg1 = B + (long)(b_row + 8) * N + n0 + b_col;

  float4 av0 = *(const float4*)(Ag0);
  float4 av1 = *(const float4*)(Ag1);
  float4 bv0 = *(const float4*)(Bg0);
  float4 bv1 = *(const float4*)(Bg1);

  float acc[8][8];
#pragma unroll
  for (int i = 0; i < 8; ++i)
#pragma unroll
    for (int j = 0; j < 8; ++j) acc[i][j] = 0.f;

  const int nt = K / BK;
  int buf = 0;

#pragma unroll
  for (int i = 0; i < 4; ++i) {
    As[0][a_kc + i][a_row]      = (&av0.x)[i];
    As[0][a_kc + i][a_row + 64] = (&av1.x)[i];
  }
  *(float4*)&Bs[0][b_row][b_col]     = bv0;
  *(float4*)&Bs[0][b_row + 8][b_col] = bv1;
  __syncthreads();

  for (int t = 0; t < nt; ++t) {
    if (t + 1 < nt) {
      const long ko = (long)(t + 1) * BK;
      av0 = *(const float4*)(Ag0 + ko);
      av1 = *(const float4*)(Ag1 + ko);
      bv0 = *(const float4*)(Bg0 + ko * N);
      bv1 = *(const float4*)(Bg1 + ko * N);
    }
    float tacc[8][8];
#pragma unroll
    for (int i = 0; i < 8; ++i)
#pragma unroll
      for (int j = 0; j < 8; ++j) tacc[i][j] = 0.f;

#pragma unroll
    for (int kk = 0; kk < BK; ++kk) {
      float4 aA = *(const float4*)&As[buf][kk][ty * 4];
      float4 aB = *(const float4*)&As[buf][kk][ty * 4 + 64];
      float4 bA = *(const float4*)&Bs[buf][kk][tx * 4];
      float4 bB = *(const float4*)&Bs[buf][kk][tx * 4 + 64];
      const float ar[8] = {aA.x, aA.y, aA.z, aA.w, aB.x, aB.y, aB.z, aB.w};
      const float br[8] = {bA.x, bA.y, bA.z, bA.w, bB.x, bB.y, bB.z, bB.w};
#pragma unroll
      for (int i = 0; i < 8; ++i)
#pragma unroll
        for (int j = 0; j < 8; ++j)
          tacc[i][j] = fmaf(ar[i], br[j], tacc[i][j]);
    }
#pragma unroll
    for (int i = 0; i < 8; ++i)
#pragma unroll
      for (int j = 0; j < 8; ++j) acc[i][j] += tacc[i][j];

    if (t + 1 < nt) {
      const int nb = buf ^ 1;
#pragma unroll
      for (int i = 0; i < 4; ++i) {
        As[nb][a_kc + i][a_row]      = (&av0.x)[i];
        As[nb][a_kc + i][a_row + 64] = (&av1.x)[i];
      }
      *(float4*)&Bs[nb][b_row][b_col]     = bv0;
      *(float4*)&Bs[nb][b_row + 8][b_col] = bv1;
    }
    __syncthreads();
    buf ^= 1;
  }

#pragma unroll
  for (int i = 0; i < 8; ++i) {
    const long row = m0 + (i < 4 ? ty * 4 + i : 64 + ty * 4 + (i - 4));
#pragma unroll
    for (int c = 0; c < 2; ++c) {
      float4 v;
      v.x = acc[i][c * 4 + 0];
      v.y = acc[i][c * 4 + 1];
      v.z = acc[i][c * 4 + 2];
      v.w = acc[i][c * 4 + 3];
      *(float4*)&C[row * N + n0 + tx * 4 + c * 64] = v;
    }
  }
}

// ---- transpose + split2 XW -> fragment-ready tiles: [split][kt][c(4)][n(256)][8] ----
__global__ __launch_bounds__(256)
void transpose_split(const float* __restrict__ XW,
                     unsigned short* __restrict__ X1,
                     unsigned short* __restrict__ X2)
{
  __shared__ float T[64][65];
  const int tid = threadIdx.x;
  const long kb = (long)blockIdx.x * 64;   // XW row (k) tile
  const long nb = (long)blockIdx.y * 64;   // XW col (n) tile

#pragma unroll
  for (int i = 0; i < 4; ++i) {
    int idx = tid + 256 * i;
    int r = idx >> 4, c4 = (idx & 15) * 4;
    float4 v = *(const float4*)&XW[(kb + r) * 256 + nb + c4];
    T[r][c4 + 0] = v.x; T[r][c4 + 1] = v.y; T[r][c4 + 2] = v.z; T[r][c4 + 3] = v.w;
  }
  __syncthreads();

#pragma unroll
  for (int i = 0; i < 2; ++i) {
    int idx = tid + 256 * i;
    int n = idx >> 3, kq = (idx & 7) * 8;   // 8 consecutive k for column nb+n
    float x[8];
#pragma unroll
    for (int j = 0; j < 8; ++j) x[j] = T[kq + j][n];
    unsigned q1[4], q2[4];
#pragma unroll
    for (int p = 0; p < 4; ++p)
      split2_pair_f16(x[2 * p], x[2 * p + 1], q1[p], q2[p]);
    const long gk = kb + kq;
    const long gt = gk >> 5;                 // 32-wide k-tile
    const int  c  = (int)((gk >> 3) & 3);    // 16B chunk within tile
    const long o  = ((gt * 4 + c) * 256 + (nb + n)) * 8;
    *(uint4*)&X1[o] = make_uint4(q1[0], q1[1], q1[2], q1[3]);
    *(uint4*)&X2[o] = make_uint4(q2[0], q2[1], q2[2], q2[3]);
  }
}

// ---------------- GEMM2: Z = adj @ XW, fp16 split-2 MFMA ----------------
// A: global f32 -> regs -> split2 -> LDS (double-buffered, 32 KB total).
// B: global (fragment-ready, L3-resident) -> VGPR directly, no LDS.
// One raw barrier/iter; only lgkmcnt(0) before it -- pa/bf global loads
// remain in flight across the barrier (compiler inserts counted vmcnt
// before their uses).

__global__ __launch_bounds__(256, 2)
void gemm_split2(const float* __restrict__ A,
                 const unsigned short* __restrict__ Bg,   // 2 splits, stride NM_
                 float* __restrict__ P0, float* __restrict__ P1)
{
  __shared__ unsigned short As[2][8192];    // 2 x 16 KB

  const int tid  = threadIdx.x;
  const int lane = tid & 63;
  const int w    = tid >> 6;
  const int wm   = w >> 1, wn = w & 1;

  // XCD swizzle: 512 blocks = 8 XCDs x 64; the 4 (n,z) blocks of one adj
  // m-panel land on the same XCD for L2 reuse of adj.
  const int bid = blockIdx.x;
  const int swz = (bid & 7) * 64 + (bid >> 3);
  const long m0 = (long)(swz >> 2) * 128;
  const long n0 = (long)((swz >> 1) & 1) * 128;
  const int  z  = swz & 1;
  float* __restrict__ Cp = z ? P1 : P0;

  // A staging: thread -> (row = tid&127, k 16*ah..16*ah+15)
  const int arow = tid & 127;
  const int ah   = tid >> 7;
  const float* Ag = A + (m0 + arow) * 16384L + (long)z * 8192 + ah * 16;

  // A LDS write offsets (ushort units within one As buffer): [s][c=2*ah+q][arow][8]
  int awr[2][2];
#pragma unroll
  for (int s = 0; s < 2; ++s)
#pragma unroll
    for (int q = 0; q < 2; ++q)
      awr[s][q] = ((s * 4 + 2 * ah + q) * 128 + arow) * 8;

  const int fr = lane & 15;
  const int kc = lane >> 4;

  // B fragment base (ushort units, before split/tile/frag offsets):
  const unsigned short* Bq = Bg + (long)kc * 2048 + ((long)n0 + wn * 64 + fr) * 8;

  floatx4 acc[4][4], accS[4][4];
#pragma unroll
  for (int i = 0; i < 4; ++i)
#pragma unroll
    for (int j = 0; j < 4; ++j) { acc[i][j] = (floatx4)0.f; accS[i][j] = (floatx4)0.f; }

  float4  pa[4];       // next A tile (f32)
  half8v  bf[2][4];    // current B fragments

#define SPLIT_WRITE(NB)                                                           \
  {                                                                               \
    unsigned q1[8], q2[8];                                                        \
    _Pragma("unroll")                                                             \
    for (int p = 0; p < 8; ++p) {                                                 \
      float x0 = (&pa[p >> 1].x)[(2 * p) & 3];                                    \
      float x1 = (&pa[p >> 1].x)[(2 * p + 1) & 3];                                \
      split2_pair_f16(x0, x1, q1[p], q2[p]);                                      \
    }                                                                             \
    *(uint4*)&As[NB][awr[0][0]] = make_uint4(q1[0], q1[1], q1[2], q1[3]);         \
    *(uint4*)&As[NB][awr[0][1]] = make_uint4(q1[4], q1[5], q1[6], q1[7]);         \
    *(uint4*)&As[NB][awr[1][0]] = make_uint4(q2[0], q2[1], q2[2], q2[3]);         \
    *(uint4*)&As[NB][awr[1][1]] = make_uint4(q2[4], q2[5], q2[6], q2[7]);         \
  }

#define LOAD_BF(TILE)                                                             \
  {                                                                               \
    const long bo_ = ((long)z * KT + (TILE)) * 8192;                              \
    _Pragma("unroll")                                                             \
    for (int s = 0; s < 2; ++s)                                                   \
      _Pragma("unroll")                                                           \
      for (int fn = 0; fn < 4; ++fn)                                              \
        bf[s][fn] = *(const half8v*)(Bq + s * NM_ + bo_ + fn * 128);              \
  }

  // BODY(TT,CUR): entry: As[CUR]=A(TT), bf=B(TT), pa=A(TT+1).
  // Splits A(TT+1)->As[CUR^1]; pa<-A(TT+2); computes TT; bf<-B(TT+1).
#define BODY(TT, CUR)                                                             \
  {                                                                               \
    SPLIT_WRITE((CUR) ^ 1);                                                       \
    {                                                                             \
      const long ko_ = (long)(((TT) + 2) & (KT - 1)) * 32;                        \
      _Pragma("unroll")                                                           \
      for (int i = 0; i < 4; ++i) pa[i] = *(const float4*)(Ag + ko_ + i * 4);     \
    }                                                                             \
    _Pragma("unroll")                                                             \
    for (int fm = 0; fm < 4; ++fm) {                                              \
      const int ar_ = (wm * 64 + fm * 16 + fr) * 8;                               \
      half8v af0 = *(const half8v*)&As[CUR][kc * 1024 + ar_];                     \
      half8v af1 = *(const half8v*)&As[CUR][(4 + kc) * 1024 + ar_];               \
      _Pragma("unroll")                                                           \
      for (int fn = 0; fn < 4; ++fn) {                                            \
        floatx4 d = acc[fm][fn];                                                  \
        d = __builtin_amdgcn_mfma_f32_16x16x32_f16(af0, bf[0][fn], d, 0, 0, 0);   \
        d = __builtin_amdgcn_mfma_f32_16x16x32_f16(af0, bf[1][fn], d, 0, 0, 0);   \
        d = __builtin_amdgcn_mfma_f32_16x16x32_f16(af1, bf[0][fn], d, 0, 0, 0);   \
        acc[fm][fn] = d;                                                          \
      }                                                                           \
    }                                                                             \
    LOAD_BF(((TT) + 1) & (KT - 1));                                               \
    if (((TT) & 31) == 31) {                                                      \
      _Pragma("unroll")                                                           \
      for (int i = 0; i < 4; ++i)                                                 \
        _Pragma("unroll")                                                         \
        for (int j = 0; j < 4; ++j) { accS[i][j] += acc[i][j]; acc[i][j] = (floatx4)0.f; } \
    }                                                                             \
    asm volatile("s_waitcnt lgkmcnt(0)" ::: "memory");                            \
    __builtin_amdgcn_s_barrier();                                                 \
    __builtin_amdgcn_sched_barrier(0);                                            \
  }

  // ---- prologue: pa<-A(0); bf<-B(0); split A(0)->As[0]; pa<-A(1) ----
#pragma unroll
  for (int i = 0; i < 4; ++i) pa[i] = *(const float4*)(Ag + i * 4);
  LOAD_BF(0);
  SPLIT_WRITE(0);
#pragma unroll
  for (int i = 0; i < 4; ++i) pa[i] = *(const float4*)(Ag + 32 + i * 4);
  asm volatile("s_waitcnt lgkmcnt(0)" ::: "memory");
  __builtin_amdgcn_s_barrier();
  __builtin_amdgcn_sched_barrier(0);

  for (int t = 0; t < KT; t += 2) {
    BODY(t,     0);
    BODY(t + 1, 1);
  }

  // epilogue: C/D layout col=lane&15, row=(lane>>4)*4+j
#pragma unroll
  for (int fm = 0; fm < 4; ++fm) {
#pragma unroll
    for (int fn = 0; fn < 4; ++fn) {
      const long col  = n0 + wn * 64 + fn * 16 + fr;
      const long rowb = m0 + wm * 64 + fm * 16 + (lane >> 4) * 4;
#pragma unroll
      for (int j = 0; j < 4; ++j)
        Cp[(rowb + j) * 256 + col] = accS[fm][fn][j];
    }
  }
#undef BODY
#undef LOAD_BF
#undef SPLIT_WRITE
}

// ---------------- P1 += P0 ----------------
__global__ __launch_bounds__(256)
void reduce_add(const float* __restrict__ P0, float* __restrict__ P1, long n4)
{
  long i = (long)blockIdx.x * 256 + threadIdx.x;
  const long stride = (long)gridDim.x * 256;
  for (; i < n4; i += stride) {
    float4 a = ((const float4*)P0)[i];
    float4 b = ((const float4*)P1)[i];
    b.x += a.x; b.y += a.y; b.z += a.z; b.w += a.w;
    ((float4*)P1)[i] = b;
  }
}

// ---------------- edge scoring ----------------
__global__ __launch_bounds__(256)
void edge_score(const float* __restrict__ Z, const float* __restrict__ w2,
                const int* __restrict__ te, const int* __restrict__ fe,
                int E, float* __restrict__ out)
{
  const long gtid = (long)blockIdx.x * 256 + threadIdx.x;
  const long wid = gtid >> 6;
  const int lane = threadIdx.x & 63;
  if (wid >= 2L * E) return;
  const int* ep = (wid < E) ? (te + 2 * wid) : (fe + 2 * (wid - E));
  const int src = ep[0];
  const int dst = ep[1];
  const float4 a = ((const float4*)(Z + (long)src * 256))[lane];
  const float4 b = ((const float4*)(Z + (long)dst * 256))[lane];
  const float4 w = ((const float4*)w2)[lane];
  float s = a.x * b.x * w.x + a.y * b.y * w.y + a.z * b.z * w.z + a.w * b.w * w.w;
#pragma unroll
  for (int off = 32; off > 0; off >>= 1) s += __shfl_down(s, off);
  if (lane == 0) out[wid] = 1.0f / (1.0f + expf(-s));
}

extern "C" void kernel_launch(void* const* d_in, const int* in_sizes, int n_in,
                              void* d_out, int out_size, void* d_ws, size_t ws_size,
                              hipStream_t stream)
{
  const float* X   = (const float*)d_in[0];
  const float* adj = (const float*)d_in[1];
  const float* W   = (const float*)d_in[2];
  const float* W2  = (const float*)d_in[3];
  const int*   te  = (const int*)d_in[4];
  const int*   fe  = (const int*)d_in[5];

  const int E = in_sizes[4] / 2;

  float* ws = (float*)d_ws;
  float* XW = ws;                    // dead after transpose_split; reused as P0
  float* P0 = ws;
  float* P1 = ws + NM_;              // final Z lives here
  unsigned short* X1 = (unsigned short*)(ws + 2 * NM_);
  unsigned short* X2 = X1 + NM_;     // gemm_split2 indexes Bg + s*NM_
  // total ws use: 2*NM*4 + 2*NM*2 = 50.3 MB

  dim3 blk(256);
  gemm_f32_nn<<<dim3(128, 2), blk, 0, stream>>>(X, W, XW, 16384, 256, 512);
  transpose_split<<<dim3(256, 4), blk, 0, stream>>>(XW, X1, X2);
  gemm_split2<<<dim3(512), blk, 0, stream>>>(adj, X1, P0, P1);
  reduce_add<<<dim3(2048), blk, 0, stream>>>(P0, P1, NM_ / 4);
  const long nwaves = 2L * E;
  const int nblocks = (int)((nwaves + 3) / 4);
  edge_score<<<dim3(nblocks), blk, 0, stream>>>(P1, W2, te, fe, E, (float*)d_out);
}